// Round 1
// 539.651 us; speedup vs baseline: 1.1028x; 1.1028x over previous
//
#include <hip/hip_runtime.h>

#define EPSF 1e-5f

typedef _Float16 f16x8 __attribute__((ext_vector_type(8)));
typedef float f32x4 __attribute__((ext_vector_type(4)));

__device__ __forceinline__ void gload_lds16(const _Float16* g, _Float16* l) {
  __builtin_amdgcn_global_load_lds(
      (const __attribute__((address_space(1))) unsigned int*)g,
      (__attribute__((address_space(3))) unsigned int*)l, 16, 0, 0);
}

__device__ __forceinline__ f16x8 cvt8(float4 a, float4 b) {
  f16x8 h;
  h[0] = (_Float16)a.x; h[1] = (_Float16)a.y; h[2] = (_Float16)a.z; h[3] = (_Float16)a.w;
  h[4] = (_Float16)b.x; h[5] = (_Float16)b.y; h[6] = (_Float16)b.z; h[7] = (_Float16)b.w;
  return h;
}

// counted waitcnt: vmcnt(N) keeps N gload_lds in flight across the barrier (T4);
// lgkmcnt(0) closes the ds_read-vs-overwrite race before the barrier.
template <int N>
__device__ __forceinline__ void wait_vm() {
  if constexpr (N == 8) asm volatile("s_waitcnt vmcnt(8) lgkmcnt(0)" ::: "memory");
  else if constexpr (N == 4) asm volatile("s_waitcnt vmcnt(4) lgkmcnt(0)" ::: "memory");
  else asm volatile("s_waitcnt vmcnt(0) lgkmcnt(0)" ::: "memory");
}

__device__ __forceinline__ void barrier_fence() {
  __builtin_amdgcn_s_barrier();
  asm volatile("" ::: "memory");
}

// ==========================================================================
// 256x256 tile, K=1024 in 32 tiles of BK=32, 8 waves (2M x 4N), ring-4 LDS
// (4 x (A 16KB + B 16KB) = 128 KiB). Deep pipeline: stage tile t+3 during
// compute of tile t; vmcnt(8) at tile boundary -> tile t+1 landed, t+2/t+3
// in flight. LDS chunk-XOR swizzle (chunk ^= row&3, 16B chunks) applied on
// the global-source side (gload_lds dest stays linear) and on ds_read side.
// Both A and B are row-major with ld = 1024 halves.
// ==========================================================================
__device__ __forceinline__ void gemm256_run(const _Float16* __restrict__ Ag,
                                            const _Float16* __restrict__ Bg,
                                            _Float16* lds, f32x4 (&acc)[8][4]) {
  const int tid = threadIdx.x;
  const int wave = tid >> 6, lane = tid & 63;
  const int wm = wave >> 2, wn = wave & 3;
  const int quad = lane >> 4, nl = lane & 15;
  const int srow = tid >> 2;                                   // 0..127 staging row in half
  const long arow = (long)srow * 1024 + (((tid & 3) ^ (srow & 3)) * 8);  // pre-swizzled src
  const int pq = (quad ^ (nl & 3)) * 8;                        // swizzled read chunk (halves)

#pragma unroll
  for (int i = 0; i < 8; ++i)
#pragma unroll
    for (int j = 0; j < 4; ++j) acc[i][j] = (f32x4){0.f, 0.f, 0.f, 0.f};

#define STAGE_A(t)                                                     \
  {                                                                    \
    _Float16* lA_ = lds + ((t) & 3) * 16384;                           \
    const _Float16* ga_ = Ag + arow + (t) * 32;                        \
    gload_lds16(ga_, lA_ + wave * 512);                                \
    gload_lds16(ga_ + 128 * 1024, lA_ + 4096 + wave * 512);            \
  }
#define STAGE_B(t)                                                     \
  {                                                                    \
    _Float16* lB_ = lds + ((t) & 3) * 16384 + 8192;                    \
    const _Float16* gb_ = Bg + arow + (t) * 32;                        \
    gload_lds16(gb_, lB_ + wave * 512);                                \
    gload_lds16(gb_ + 128 * 1024, lB_ + 4096 + wave * 512);            \
  }
#define LDA(t, mq, af)                                                 \
  {                                                                    \
    const _Float16* p_ =                                               \
        lds + ((t) & 3) * 16384 + (wm * 128 + (mq) * 64 + nl) * 32 + pq; \
    _Pragma("unroll") for (int i_ = 0; i_ < 4; ++i_)                   \
        af[i_] = *(const f16x8*)(p_ + i_ * 512);                       \
  }
#define LDB(t, bf)                                                     \
  {                                                                    \
    const _Float16* p_ =                                               \
        lds + ((t) & 3) * 16384 + 8192 + (wn * 64 + nl) * 32 + pq;     \
    _Pragma("unroll") for (int i_ = 0; i_ < 4; ++i_)                   \
        bf[i_] = *(const f16x8*)(p_ + i_ * 512);                       \
  }
#define MMA(mq, af, bf)                                                \
  {                                                                    \
    __builtin_amdgcn_s_setprio(1);                                     \
    _Pragma("unroll") for (int i_ = 0; i_ < 4; ++i_)                   \
        _Pragma("unroll") for (int j_ = 0; j_ < 4; ++j_)               \
            acc[(mq) * 4 + i_][j_] = __builtin_amdgcn_mfma_f32_16x16x32_f16( \
                af[i_], bf[j_], acc[(mq) * 4 + i_][j_], 0, 0, 0);      \
    __builtin_amdgcn_s_setprio(0);                                     \
  }
#define TILE(t, STG)                                                   \
  {                                                                    \
    f16x8 af_[4], bf_[4];                                              \
    LDA(t, 0, af_);                                                    \
    LDB(t, bf_);                                                       \
    if (STG) STAGE_A((t) + 3);                                         \
    MMA(0, af_, bf_);                                                  \
    f16x8 af2_[4];                                                     \
    LDA(t, 1, af2_);                                                   \
    if (STG) STAGE_B((t) + 3);                                         \
    MMA(1, af2_, bf_);                                                 \
  }

  // prologue: stage tiles 0,1,2 (12 loads in flight); vmcnt(8) -> tile0 landed
  STAGE_A(0); STAGE_B(0);
  STAGE_A(1); STAGE_B(1);
  STAGE_A(2); STAGE_B(2);
  wait_vm<8>();
  barrier_fence();

#pragma unroll 4
  for (int t = 0; t < 28; ++t) {
    TILE(t, true);          // stages tile t+3 into ring[(t+3)&3] (freed at end of t-1)
    wait_vm<8>();           // tile t+1 landed; t+2, t+3 stay in flight
    barrier_fence();
  }
  TILE(28, true);           // stages tile 31
  wait_vm<8>(); barrier_fence();
  TILE(29, false);
  wait_vm<4>(); barrier_fence();
  TILE(30, false);
  wait_vm<0>(); barrier_fence();
  TILE(31, false);

#undef TILE
#undef MMA
#undef LDB
#undef LDA
#undef STAGE_B
#undef STAGE_A
}

// ================= kernel 0a: opinion weights =================
__global__ void prep_opin_k(const float* __restrict__ gold, const float* __restrict__ pred,
                            const float* __restrict__ gprob, float* __restrict__ opin, int n) {
  int i = blockIdx.x * 256 + threadIdx.x;
  if (i >= n) return;
  float gp = gprob[0];
  float go = gold[i * 5 + 1] + gold[i * 5 + 2];
  float po = pred[i * 5 + 3] + pred[i * 5 + 4];
  opin[i] = gp * go + (1.0f - gp) * po;
}

// ================= kernel 0b: fp32 -> fp16 copy (x->Xh, W->Wh) =================
__global__ __launch_bounds__(256) void prep_h_k(const float* __restrict__ src,
                                                _Float16* __restrict__ dst) {
  long i = ((long)blockIdx.x * 256 + threadIdx.x) * 8;
  float4 a = *(const float4*)(src + i);
  float4 b = *(const float4*)(src + i + 4);
  *(f16x8*)(dst + i) = cvt8(a, b);
}

// ================= kernel 0c: XhT[b][d][t] = fp16(x[b][t][d]) =================
__global__ __launch_bounds__(256) void prep_xt_k(const float* __restrict__ x,
                                                 _Float16* __restrict__ XhT) {
  const int d = blockIdx.x * 256 + threadIdx.x;
  const int ts = blockIdx.y * 64;
  const long base = (long)blockIdx.z * 1024;
#pragma unroll
  for (int tg = 0; tg < 4; ++tg) {
    int t0 = ts + tg * 16;
    const float* src = x + (base + t0) * 1024 + d;
    float v[16];
#pragma unroll
    for (int j = 0; j < 16; ++j) v[j] = src[j * 1024];
    f16x8 h0, h1;
#pragma unroll
    for (int j = 0; j < 8; ++j) { h0[j] = (_Float16)v[j]; h1[j] = (_Float16)v[8 + j]; }
    _Float16* dst = XhT + (base + d) * 1024 + t0;
    *(f16x8*)dst = h0;
    *(f16x8*)(dst + 8) = h1;
  }
}

// ================= kernel 1 (big): XT = fp16(Xh @ Wh^T + b), 256^2 pipelined ====
// XCD swizzle: class = lin&7 owns 16 consecutive m-tiles (A panels shared in L2).
__global__ __launch_bounds__(512, 2) void gemm12_k(const _Float16* __restrict__ Xh,
                                                   const _Float16* __restrict__ Wh,
                                                   const float* __restrict__ bias,
                                                   _Float16* __restrict__ XT) {
  __shared__ _Float16 lds[4 * 16384];
  const int lin = blockIdx.x;
  const int ii = lin >> 3;
  const int mt = (lin & 7) * 16 + (ii >> 2);
  const int nt = ii & 3;
  const long m0 = (long)mt * 256;
  const int n0 = nt * 256;

  f32x4 acc[8][4];
  gemm256_run(Xh + m0 * 1024, Wh + (long)n0 * 1024, lds, acc);

  const int tid = threadIdx.x;
  const int wave = tid >> 6, lane = tid & 63;
  const int wm = wave >> 2, wn = wave & 3;
  const int quad = lane >> 4, nl = lane & 15;
#pragma unroll
  for (int mi = 0; mi < 8; ++mi) {
    long gm = m0 + wm * 128 + mi * 16 + quad * 4;
#pragma unroll
    for (int ni = 0; ni < 4; ++ni) {
      int gn = n0 + wn * 64 + ni * 16 + nl;
      float bv = bias[gn];
#pragma unroll
      for (int r = 0; r < 4; ++r)
        XT[(gm + r) * 1024 + gn] = (_Float16)(acc[mi][ni][r] + bv);
    }
  }
}

// ================= kernel 2 (big): P = fp16(exp(tanh(XT@Xh^T * decay * opin))) ====
// XCD swizzle: class = lin&7 -> 4 batches, 16 tiles/batch consecutive (4MB/XCD L2).
__global__ __launch_bounds__(512, 2) void scores2_k(const _Float16* __restrict__ XT,
                                                    const _Float16* __restrict__ Xh,
                                                    const float* __restrict__ opin,
                                                    _Float16* __restrict__ P,
                                                    float* __restrict__ denom) {
  __shared__ _Float16 lds[4 * 16384];
  const int lin = blockIdx.x;
  const int ii = lin >> 3;
  const int b = (lin & 7) + 8 * (ii >> 4);
  const int tile = ii & 15;
  const int s0 = (tile >> 2) * 256;
  const int t0 = (tile & 3) * 256;
  const long base = (long)b * 1024;

  f32x4 acc[8][4];
  gemm256_run(XT + (base + s0) * 1024, Xh + (base + t0) * 1024, lds, acc);

  const int tid = threadIdx.x;
  const int wave = tid >> 6, lane = tid & 63;
  const int wm = wave >> 2, wn = wave & 3;
  const int quad = lane >> 4, nl = lane & 15;
#pragma unroll
  for (int mi = 0; mi < 8; ++mi) {
#pragma unroll
    for (int r = 0; r < 4; ++r) {
      int s = s0 + wm * 128 + mi * 16 + quad * 4 + r;
      float opv = opin[b * 1024 + s];
      float rs = 0.f;
#pragma unroll
      for (int ni = 0; ni < 4; ++ni) {
        int tc = t0 + wn * 64 + ni * 16 + nl;
        float loc = fabsf((float)(s - tc));
        float arg = acc[mi][ni][r] * (1.0f / (loc + EPSF)) * opv;
        float th = 1.f - 2.f / (__expf(2.f * arg) + 1.f);  // tanh(arg)
        float p = __expf(th);
        if (s == tc) p = 0.f;
        P[(base + s) * 1024 + tc] = (_Float16)p;
        rs += p;
      }
      rs += __shfl_xor(rs, 1);
      rs += __shfl_xor(rs, 2);
      rs += __shfl_xor(rs, 4);
      rs += __shfl_xor(rs, 8);
      if (nl == 0) atomicAdd(&denom[b * 1024 + s], rs);
    }
  }
}

// ================= kernel 3 (big): out = (P @ XhT^T) / (denom + eps) ==========
__global__ __launch_bounds__(512, 2) void pv2_k(const _Float16* __restrict__ P,
                                                const _Float16* __restrict__ XhT,
                                                const float* __restrict__ denom,
                                                float* __restrict__ out) {
  __shared__ _Float16 lds[4 * 16384];
  const int lin = blockIdx.x;
  const int ii = lin >> 3;
  const int b = (lin & 7) + 8 * (ii >> 4);
  const int tile = ii & 15;
  const int s0 = (tile >> 2) * 256;
  const int d0 = (tile & 3) * 256;
  const long base = (long)b * 1024;

  f32x4 acc[8][4];
  gemm256_run(P + (base + s0) * 1024, XhT + (base + d0) * 1024, lds, acc);

  const int tid = threadIdx.x;
  const int wave = tid >> 6, lane = tid & 63;
  const int wm = wave >> 2, wn = wave & 3;
  const int quad = lane >> 4, nl = lane & 15;
#pragma unroll
  for (int mi = 0; mi < 8; ++mi) {
#pragma unroll
    for (int r = 0; r < 4; ++r) {
      int s = s0 + wm * 128 + mi * 16 + quad * 4 + r;
      float inv = 1.0f / (denom[b * 1024 + s] + EPSF);
#pragma unroll
      for (int ni = 0; ni < 4; ++ni) {
        int d = d0 + wn * 64 + ni * 16 + nl;
        out[(base + s) * 1024 + d] = acc[mi][ni][r] * inv;
      }
    }
  }
}

// =================== fallback path (small ws) — unchanged 128^2 kernels =========
__global__ __launch_bounds__(256) void gemm1_k(const _Float16* __restrict__ Xh,
                                               const float* __restrict__ Wt,
                                               const float* __restrict__ bias,
                                               _Float16* __restrict__ XT) {
  __shared__ _Float16 As[128 * 32];
  __shared__ _Float16 Bs[128 * 32];
  const int tid = threadIdx.x;
  const int wave = tid >> 6, lane = tid & 63;
  const int wm = wave >> 1, wn = wave & 1;
  const int quad = lane >> 4, nl = lane & 15;
  const long m0 = (long)blockIdx.y * 128;
  const int n0 = blockIdx.x * 128;

  f32x4 acc[4][4];
  f32x4 zero = {0.f, 0.f, 0.f, 0.f};
#pragma unroll
  for (int i = 0; i < 4; ++i)
#pragma unroll
    for (int j = 0; j < 4; ++j) acc[i][j] = zero;

  const int crow = tid >> 2;
  const int ckc = (tid & 3) * 8;

  for (int k0 = 0; k0 < 1024; k0 += 32) {
#pragma unroll
    for (int it = 0; it < 2; ++it) {
      int c = it * 256 + tid;
      gload_lds16(Xh + (m0 + (c >> 2)) * 1024 + k0 + (c & 3) * 8,
                  &As[(it * 256 + wave * 64) * 8]);
      int row = it * 64 + crow;
      const float* sb = Wt + (long)(n0 + row) * 1024 + k0 + ckc;
      float4 b0 = *(const float4*)sb;
      float4 b1 = *(const float4*)(sb + 4);
      *(f16x8*)&Bs[row * 32 + ckc] = cvt8(b0, b1);
    }
    __syncthreads();
    f16x8 af[4], bf[4];
#pragma unroll
    for (int mi = 0; mi < 4; ++mi)
      af[mi] = *(const f16x8*)&As[(wm * 64 + mi * 16 + nl) * 32 + quad * 8];
#pragma unroll
    for (int ni = 0; ni < 4; ++ni)
      bf[ni] = *(const f16x8*)&Bs[(wn * 64 + ni * 16 + nl) * 32 + quad * 8];
#pragma unroll
    for (int mi = 0; mi < 4; ++mi)
#pragma unroll
      for (int ni = 0; ni < 4; ++ni)
        acc[mi][ni] = __builtin_amdgcn_mfma_f32_16x16x32_f16(af[mi], bf[ni], acc[mi][ni], 0, 0, 0);
    __syncthreads();
  }

#pragma unroll
  for (int mi = 0; mi < 4; ++mi) {
    long gm = m0 + wm * 64 + mi * 16 + quad * 4;
#pragma unroll
    for (int ni = 0; ni < 4; ++ni) {
      int gn = n0 + wn * 64 + ni * 16 + nl;
      float bv = bias[gn];
#pragma unroll
      for (int r = 0; r < 4; ++r)
        XT[(gm + r) * 1024 + gn] = (_Float16)(acc[mi][ni][r] + bv);
    }
  }
}

__global__ __launch_bounds__(256) void scores_f_k(const _Float16* __restrict__ XT,
                                                  const _Float16* __restrict__ Xh,
                                                  const float* __restrict__ opin,
                                                  _Float16* __restrict__ P,
                                                  float* __restrict__ denom) {
  __shared__ _Float16 As[128 * 32];
  __shared__ _Float16 Bs[128 * 32];
  const int tid = threadIdx.x;
  const int wave = tid >> 6, lane = tid & 63;
  const int wm = wave >> 1, wn = wave & 1;
  const int quad = lane >> 4, nl = lane & 15;
  const int b = blockIdx.z;
  const int s0 = blockIdx.y * 128;
  const int t0 = blockIdx.x * 128;
  const long base = (long)b * 1024;

  f32x4 acc[4][4];
  f32x4 zero = {0.f, 0.f, 0.f, 0.f};
#pragma unroll
  for (int i = 0; i < 4; ++i)
#pragma unroll
    for (int j = 0; j < 4; ++j) acc[i][j] = zero;

  for (int k0 = 0; k0 < 1024; k0 += 32) {
#pragma unroll
    for (int it = 0; it < 2; ++it) {
      int c = it * 256 + tid;
      gload_lds16(XT + (base + s0 + (c >> 2)) * 1024 + k0 + (c & 3) * 8,
                  &As[(it * 256 + wave * 64) * 8]);
      gload_lds16(Xh + (base + t0 + (c >> 2)) * 1024 + k0 + (c & 3) * 8,
                  &Bs[(it * 256 + wave * 64) * 8]);
    }
    __syncthreads();
    f16x8 af[4], bf[4];
#pragma unroll
    for (int mi = 0; mi < 4; ++mi)
      af[mi] = *(const f16x8*)&As[(wm * 64 + mi * 16 + nl) * 32 + quad * 8];
#pragma unroll
    for (int ni = 0; ni < 4; ++ni)
      bf[ni] = *(const f16x8*)&Bs[(wn * 64 + ni * 16 + nl) * 32 + quad * 8];
#pragma unroll
    for (int mi = 0; mi < 4; ++mi)
#pragma unroll
      for (int ni = 0; ni < 4; ++ni)
        acc[mi][ni] = __builtin_amdgcn_mfma_f32_16x16x32_f16(af[mi], bf[ni], acc[mi][ni], 0, 0, 0);
    __syncthreads();
  }

#pragma unroll
  for (int mi = 0; mi < 4; ++mi) {
#pragma unroll
    for (int r = 0; r < 4; ++r) {
      int s = s0 + wm * 64 + mi * 16 + quad * 4 + r;
      float opv = opin[b * 1024 + s];
      float rs = 0.f;
#pragma unroll
      for (int ni = 0; ni < 4; ++ni) {
        int t = t0 + wn * 64 + ni * 16 + nl;
        float loc = fabsf((float)(s - t));
        float arg = acc[mi][ni][r] * (1.0f / (loc + EPSF)) * opv;
        float th = 1.f - 2.f / (__expf(2.f * arg) + 1.f);
        float p = __expf(th);
        if (s == t) p = 0.f;
        P[(base + s) * 1024 + t] = (_Float16)p;
        rs += p;
      }
      rs += __shfl_xor(rs, 1);
      rs += __shfl_xor(rs, 2);
      rs += __shfl_xor(rs, 4);
      rs += __shfl_xor(rs, 8);
      if (nl == 0) atomicAdd(&denom[b * 1024 + s], rs);
    }
  }
}

__global__ __launch_bounds__(256) void pv_k(const _Float16* __restrict__ P,
                                            const float* __restrict__ X,
                                            const float* __restrict__ denom,
                                            float* __restrict__ out) {
  __shared__ _Float16 As[128 * 32];
  __shared__ _Float16 BsT[128 * 40];
  const int tid = threadIdx.x;
  const int wave = tid >> 6, lane = tid & 63;
  const int wm = wave >> 1, wn = wave & 1;
  const int quad = lane >> 4, nl = lane & 15;
  const int b = blockIdx.z;
  const int s0 = blockIdx.y * 128;
  const int d0 = blockIdx.x * 128;
  const long base = (long)b * 1024;

  const int dcol = tid & 127;
  const int tg = tid >> 7;

  f32x4 acc[4][4];
  f32x4 zero = {0.f, 0.f, 0.f, 0.f};
#pragma unroll
  for (int i = 0; i < 4; ++i)
#pragma unroll
    for (int j = 0; j < 4; ++j) acc[i][j] = zero;

  for (int k0 = 0; k0 < 1024; k0 += 32) {
#pragma unroll
    for (int it = 0; it < 2; ++it) {
      int c = it * 256 + tid;
      gload_lds16(P + (base + s0 + (c >> 2)) * 1024 + k0 + (c & 3) * 8,
                  &As[(it * 256 + wave * 64) * 8]);
    }
    {
      const float* xb = X + (base + k0 + tg * 16) * 1024 + d0 + dcol;
      float v[16];
#pragma unroll
      for (int j = 0; j < 16; ++j) v[j] = xb[j * 1024];
      f16x8 h0, h1;
#pragma unroll
      for (int j = 0; j < 8; ++j) { h0[j] = (_Float16)v[j]; h1[j] = (_Float16)v[8 + j]; }
      *(f16x8*)&BsT[dcol * 40 + tg * 16] = h0;
      *(f16x8*)&BsT[dcol * 40 + tg * 16 + 8] = h1;
    }
    __syncthreads();
    f16x8 af[4], bf[4];
#pragma unroll
    for (int mi = 0; mi < 4; ++mi)
      af[mi] = *(const f16x8*)&As[(wm * 64 + mi * 16 + nl) * 32 + quad * 8];
#pragma unroll
    for (int ni = 0; ni < 4; ++ni)
      bf[ni] = *(const f16x8*)&BsT[(wn * 64 + ni * 16 + nl) * 40 + quad * 8];
#pragma unroll
    for (int mi = 0; mi < 4; ++mi)
#pragma unroll
      for (int ni = 0; ni < 4; ++ni)
        acc[mi][ni] = __builtin_amdgcn_mfma_f32_16x16x32_f16(af[mi], bf[ni], acc[mi][ni], 0, 0, 0);
    __syncthreads();
  }

#pragma unroll
  for (int mi = 0; mi < 4; ++mi) {
#pragma unroll
    for (int r = 0; r < 4; ++r) {
      int s = s0 + wm * 64 + mi * 16 + quad * 4 + r;
      float inv = 1.0f / (denom[b * 1024 + s] + EPSF);
#pragma unroll
      for (int ni = 0; ni < 4; ++ni) {
        int d = d0 + wn * 64 + ni * 16 + nl;
        out[(base + s) * 1024 + d] = acc[mi][ni][r] * inv;
      }
    }
  }
}

extern "C" void kernel_launch(void* const* d_in, const int* in_sizes, int n_in,
                              void* d_out, int out_size, void* d_ws, size_t ws_size,
                              hipStream_t stream) {
  (void)in_sizes; (void)n_in; (void)out_size;
  const int B = 32, S = 1024;
  const int BS = B * S;

  const float* x     = (const float*)d_in[0];
  const float* W     = (const float*)d_in[1];
  const float* bias  = (const float*)d_in[2];
  const float* gold  = (const float*)d_in[3];
  const float* pred  = (const float*)d_in[4];
  const float* gprob = (const float*)d_in[5];

  const size_t P_BYTES  = (size_t)BS * 1024 * sizeof(_Float16);   // 64 MB
  const size_t XT_BYTES = P_BYTES;                                // 64 MB
  const size_t OPIN_B   = (size_t)BS * sizeof(float);             // 128 KB
  const size_t WH_B     = (size_t)1024 * 1024 * sizeof(_Float16); // 2 MB
  const size_t NEED_BIG = P_BYTES + XT_BYTES + 2 * OPIN_B + WH_B;

  char* ws = (char*)d_ws;
  _Float16* P = (_Float16*)ws;
  const bool big = ws_size >= NEED_BIG;

  // d_out double-duty: front 64MB = XT (fp16), back 64MB = Xh (fp16);
  // both dead before the PV kernel overwrites d_out with fp32 output.
  _Float16* XT = (_Float16*)d_out;
  _Float16* Xh = XT + (size_t)BS * 1024;
  float* out   = (float*)d_out;

  if (big) {
    _Float16* XhT = (_Float16*)(ws + P_BYTES);
    float* opin   = (float*)(ws + P_BYTES + XT_BYTES);
    float* denom  = opin + BS;
    _Float16* Wh  = (_Float16*)(ws + P_BYTES + XT_BYTES + 2 * OPIN_B);

    hipMemsetAsync(denom, 0, OPIN_B, stream);
    prep_opin_k<<<BS / 256, 256, 0, stream>>>(gold, pred, gprob, opin, BS);
    prep_h_k<<<(BS * 1024 / 8) / 256, 256, 0, stream>>>(x, Xh);
    prep_h_k<<<(1024 * 1024 / 8) / 256, 256, 0, stream>>>(W, Wh);
    prep_xt_k<<<dim3(4, 16, 32), 256, 0, stream>>>(x, XhT);
    gemm12_k<<<512, 512, 0, stream>>>(Xh, Wh, bias, XT);
    scores2_k<<<512, 512, 0, stream>>>(XT, Xh, opin, P, denom);
    pv2_k<<<512, 512, 0, stream>>>(P, XhT, denom, out);
  } else {
    float* opin  = (float*)(ws + P_BYTES);
    float* denom = opin + BS;

    hipMemsetAsync(denom, 0, OPIN_B, stream);
    prep_opin_k<<<BS / 256, 256, 0, stream>>>(gold, pred, gprob, opin, BS);
    prep_h_k<<<(BS * 1024 / 8) / 256, 256, 0, stream>>>(x, Xh);
    gemm1_k<<<dim3(8, 256), 256, 0, stream>>>(Xh, W, bias, XT);
    scores_f_k<<<dim3(8, 8, 32), 256, 0, stream>>>(XT, Xh, opin, P, denom);
    pv_k<<<dim3(8, 8, 32), 256, 0, stream>>>(P, x, denom, out);
  }
}

// Round 2
// 513.012 us; speedup vs baseline: 1.1600x; 1.0519x over previous
//
#include <hip/hip_runtime.h>

#define EPSF 1e-5f

typedef _Float16 f16x8 __attribute__((ext_vector_type(8)));
typedef float f32x4 __attribute__((ext_vector_type(4)));

__device__ __forceinline__ void gload_lds16(const _Float16* g, _Float16* l) {
  __builtin_amdgcn_global_load_lds(
      (const __attribute__((address_space(1))) unsigned int*)g,
      (__attribute__((address_space(3))) unsigned int*)l, 16, 0, 0);
}

__device__ __forceinline__ f16x8 cvt8(float4 a, float4 b) {
  f16x8 h;
  h[0] = (_Float16)a.x; h[1] = (_Float16)a.y; h[2] = (_Float16)a.z; h[3] = (_Float16)a.w;
  h[4] = (_Float16)b.x; h[5] = (_Float16)b.y; h[6] = (_Float16)b.z; h[7] = (_Float16)b.w;
  return h;
}

// ==========================================================================
// 256x256 tile, K=1024 as 16 tiles of BK=64, 8 waves (2M x 4N), ring-2 LDS
// (2 x (A 32KB + B 32KB) = 128 KiB). m201-style 4-phase/tile interleave:
//   phase = { ds_read frags | stage 2 chunks of tile T+1 | bar | lgkm(0) |
//             setprio(1) 16 MFMA setprio(0) | [vmcnt(2)] | bar }
// Counted vmcnt(2) only at phase0-end and phase3-end (never 0 in-loop).
// Per-wave stage FIFO: B0,B1 | A0,A2 | B2,B3 | A1,A3  ->
//   end-p3 vmcnt(2) drains B0..B3,A0,A2 (all p0 needs), leaves A1,A3;
//   end-p0 vmcnt(2) drains A1,A3 (p1/p3 mq1 needs).
// LDS swizzle (T2, both-sides per rule #21): 128B rows, 16B chunk c at row r
// holds logical chunk c^(r&7). Staged via inverse-permuted per-lane global
// source (gload_lds dest linear); ds_read applies the same XOR -> 2-way max.
// ==========================================================================
__device__ __forceinline__ void gemm256_run(const _Float16* __restrict__ Ag,
                                            const _Float16* __restrict__ Bg,
                                            _Float16* lds, f32x4 (&acc)[8][4]) {
  const int tid = threadIdx.x;
  const int wave = tid >> 6, lane = tid & 63;
  const int wm = wave >> 2, wn = wave & 3;
  const int quad = lane >> 4, nl = lane & 15;
  const int swz = nl & 7;  // = row&7 for all fragment rows this lane reads
  // staging: chunk q = 64 rows x 128B; wave covers rows w*8..w*8+7; lane l:
  // row = q*64 + w*8 + (l>>3), LDS slot c = l&7 must hold logical chunk
  // (l&7)^(row&7) = (l&7)^(l>>3)  -> pre-swizzled global source.
  const long stg_off = (long)(wave * 8 + (lane >> 3)) * 1024 +
                       (((lane & 7) ^ (lane >> 3)) * 8);

#pragma unroll
  for (int i = 0; i < 8; ++i)
#pragma unroll
    for (int j = 0; j < 4; ++j) acc[i][j] = (f32x4){0.f, 0.f, 0.f, 0.f};

  f16x8 af[4], bf[4];

#define STG(G, T1, q, isB)                                                   \
  gload_lds16((G) + (long)(q) * 65536 + stg_off + (T1) * 64,                 \
              lds + (((T1) & 1) * 32768 + (isB) * 16384 + (q) * 4096 + wave * 512))
#define LDB4(bb, ksub)                                                       \
  {                                                                          \
    const _Float16* pB_ = lds + (bb) * 32768 + 16384 + (wn * 64 + nl) * 64 + \
                          ((((ksub) * 4 + quad) ^ swz) * 8);                 \
    _Pragma("unroll") for (int j_ = 0; j_ < 4; ++j_)                         \
        bf[j_] = *(const f16x8*)(pB_ + j_ * 1024);                           \
  }
#define LDA4(bb, mq, ksub)                                                   \
  {                                                                          \
    const _Float16* pA_ = lds + (bb) * 32768 +                               \
                          (wm * 128 + (mq) * 64 + nl) * 64 +                 \
                          ((((ksub) * 4 + quad) ^ swz) * 8);                 \
    _Pragma("unroll") for (int i_ = 0; i_ < 4; ++i_)                         \
        af[i_] = *(const f16x8*)(pA_ + i_ * 1024);                           \
  }
#define MFMA16(mq)                                                           \
  {                                                                          \
    __builtin_amdgcn_s_setprio(1);                                           \
    _Pragma("unroll") for (int i_ = 0; i_ < 4; ++i_)                         \
        _Pragma("unroll") for (int j_ = 0; j_ < 4; ++j_)                     \
            acc[(mq) * 4 + i_][j_] = __builtin_amdgcn_mfma_f32_16x16x32_f16( \
                af[i_], bf[j_], acc[(mq) * 4 + i_][j_], 0, 0, 0);            \
    __builtin_amdgcn_s_setprio(0);                                           \
  }
#define BAR __builtin_amdgcn_s_barrier()
#define LGKM0 asm volatile("s_waitcnt lgkmcnt(0)" ::: "memory")
#define VMW2 asm volatile("s_waitcnt vmcnt(2)" ::: "memory")
#define VMW0 asm volatile("s_waitcnt vmcnt(0)" ::: "memory")

  // prologue: stage tile 0 in steady-state FIFO order
  STG(Bg, 0, 0, 1); STG(Bg, 0, 1, 1);
  STG(Ag, 0, 0, 0); STG(Ag, 0, 2, 0);
  STG(Bg, 0, 2, 1); STG(Bg, 0, 3, 1);
  STG(Ag, 0, 1, 0); STG(Ag, 0, 3, 0);
  VMW2;
  BAR;

#pragma unroll 2
  for (int T = 0; T < 15; ++T) {
    const int bb = T & 1;
    // p0: mq0,k0
    LDB4(bb, 0); LDA4(bb, 0, 0);
    STG(Bg, T + 1, 0, 1); STG(Bg, T + 1, 1, 1);
    BAR; LGKM0; MFMA16(0); VMW2; BAR;
    // p1: mq1,k0
    LDA4(bb, 1, 0);
    STG(Ag, T + 1, 0, 0); STG(Ag, T + 1, 2, 0);
    BAR; LGKM0; MFMA16(1); BAR;
    // p2: mq0,k1
    LDB4(bb, 1); LDA4(bb, 0, 1);
    STG(Bg, T + 1, 2, 1); STG(Bg, T + 1, 3, 1);
    BAR; LGKM0; MFMA16(0); BAR;
    // p3: mq1,k1
    LDA4(bb, 1, 1);
    STG(Ag, T + 1, 1, 0); STG(Ag, T + 1, 3, 0);
    BAR; LGKM0; MFMA16(1); VMW2; BAR;
  }
  {  // tile 15: no staging; drain the last 2 in-flight at p0-end
    LDB4(1, 0); LDA4(1, 0, 0);
    BAR; LGKM0; MFMA16(0); VMW0; BAR;
    LDA4(1, 1, 0);
    BAR; LGKM0; MFMA16(1); BAR;
    LDB4(1, 1); LDA4(1, 0, 1);
    BAR; LGKM0; MFMA16(0); BAR;
    LDA4(1, 1, 1);
    BAR; LGKM0; MFMA16(1); BAR;
  }
#undef VMW0
#undef VMW2
#undef LGKM0
#undef BAR
#undef MFMA16
#undef LDA4
#undef LDB4
#undef STG
}

// ================= kernel 0a: opinion weights =================
__global__ void prep_opin_k(const float* __restrict__ gold, const float* __restrict__ pred,
                            const float* __restrict__ gprob, float* __restrict__ opin, int n) {
  int i = blockIdx.x * 256 + threadIdx.x;
  if (i >= n) return;
  float gp = gprob[0];
  float go = gold[i * 5 + 1] + gold[i * 5 + 2];
  float po = pred[i * 5 + 3] + pred[i * 5 + 4];
  opin[i] = gp * go + (1.0f - gp) * po;
}

// ================= kernel 0b: fp32 -> fp16 copy (x->Xh, W->Wh) =================
__global__ __launch_bounds__(256) void prep_h_k(const float* __restrict__ src,
                                                _Float16* __restrict__ dst) {
  long i = ((long)blockIdx.x * 256 + threadIdx.x) * 8;
  float4 a = *(const float4*)(src + i);
  float4 b = *(const float4*)(src + i + 4);
  *(f16x8*)(dst + i) = cvt8(a, b);
}

// ========== kernel 0c: XhT[b][d][t] = fp16(x[b][t][d]) via LDS transpose ======
// 64x64 tile per block; coalesced 256B reads, coalesced 128B fp16 writes.
__global__ __launch_bounds__(256) void prep_xt_k(const float* __restrict__ x,
                                                 _Float16* __restrict__ XhT) {
  __shared__ _Float16 T[64][66];  // ld=66: banks (c*33+d/2)%32 -> 2-way max
  const int d0 = blockIdx.x * 64, t0 = blockIdx.y * 64;
  const long base = (long)blockIdx.z * 1024;
  const int c = threadIdx.x & 63, tr = threadIdx.x >> 6;
#pragma unroll
  for (int k = 0; k < 16; ++k) {
    int t = k * 4 + tr;
    T[t][c] = (_Float16)x[(base + t0 + t) * 1024 + d0 + c];
  }
  __syncthreads();
#pragma unroll
  for (int k = 0; k < 16; ++k) {
    int d = k * 4 + tr;
    XhT[(base + d0 + d) * 1024 + t0 + c] = T[c][d];
  }
}

// ================= kernel 1 (big): XT = fp16(Xh @ Wh^T + b) ====================
// XCD swizzle: class = lin&7 owns 16 consecutive m-tiles (A panels in-XCD).
__global__ __launch_bounds__(512, 2) void gemm12_k(const _Float16* __restrict__ Xh,
                                                   const _Float16* __restrict__ Wh,
                                                   const float* __restrict__ bias,
                                                   _Float16* __restrict__ XT) {
  __shared__ _Float16 lds[2 * 32768];
  const int lin = blockIdx.x;
  const int ii = lin >> 3;
  const int mt = (lin & 7) * 16 + (ii >> 2);
  const int nt = ii & 3;
  const long m0 = (long)mt * 256;
  const int n0 = nt * 256;

  f32x4 acc[8][4];
  gemm256_run(Xh + m0 * 1024, Wh + (long)n0 * 1024, lds, acc);

  const int tid = threadIdx.x;
  const int wave = tid >> 6, lane = tid & 63;
  const int wm = wave >> 2, wn = wave & 3;
  const int quad = lane >> 4, nl = lane & 15;
#pragma unroll
  for (int mi = 0; mi < 8; ++mi) {
    long gm = m0 + wm * 128 + mi * 16 + quad * 4;
#pragma unroll
    for (int ni = 0; ni < 4; ++ni) {
      int gn = n0 + wn * 64 + ni * 16 + nl;
      float bv = bias[gn];
#pragma unroll
      for (int r = 0; r < 4; ++r)
        XT[(gm + r) * 1024 + gn] = (_Float16)(acc[mi][ni][r] + bv);
    }
  }
}

// ======= kernel 2 (big): P = fp16(exp(tanh(XT@Xh^T * decay * opin))) ==========
// XCD swizzle: class = lin&7 -> 4 batches, 16 tiles/batch (4MB/XCD L2).
__global__ __launch_bounds__(512, 2) void scores2_k(const _Float16* __restrict__ XT,
                                                    const _Float16* __restrict__ Xh,
                                                    const float* __restrict__ opin,
                                                    _Float16* __restrict__ P,
                                                    float* __restrict__ denom) {
  __shared__ _Float16 lds[2 * 32768];
  const int lin = blockIdx.x;
  const int ii = lin >> 3;
  const int b = (lin & 7) + 8 * (ii >> 4);
  const int tile = ii & 15;
  const int s0 = (tile >> 2) * 256;
  const int t0 = (tile & 3) * 256;
  const long base = (long)b * 1024;

  f32x4 acc[8][4];
  gemm256_run(XT + (base + s0) * 1024, Xh + (base + t0) * 1024, lds, acc);

  const int tid = threadIdx.x;
  const int wave = tid >> 6, lane = tid & 63;
  const int wm = wave >> 2, wn = wave & 3;
  const int quad = lane >> 4, nl = lane & 15;
#pragma unroll
  for (int mi = 0; mi < 8; ++mi) {
#pragma unroll
    for (int r = 0; r < 4; ++r) {
      int s = s0 + wm * 128 + mi * 16 + quad * 4 + r;
      float opv = opin[b * 1024 + s];
      float rs = 0.f;
#pragma unroll
      for (int ni = 0; ni < 4; ++ni) {
        int tc = t0 + wn * 64 + ni * 16 + nl;
        float loc = fabsf((float)(s - tc));
        float arg = acc[mi][ni][r] * (1.0f / (loc + EPSF)) * opv;
        float th = 1.f - 2.f / (__expf(2.f * arg) + 1.f);  // tanh(arg)
        float p = __expf(th);
        if (s == tc) p = 0.f;
        P[(base + s) * 1024 + tc] = (_Float16)p;
        rs += p;
      }
      rs += __shfl_xor(rs, 1);
      rs += __shfl_xor(rs, 2);
      rs += __shfl_xor(rs, 4);
      rs += __shfl_xor(rs, 8);
      if (nl == 0) atomicAdd(&denom[b * 1024 + s], rs);
    }
  }
}

// ================= kernel 3 (big): out = (P @ XhT^T) / (denom + eps) ==========
__global__ __launch_bounds__(512, 2) void pv2_k(const _Float16* __restrict__ P,
                                                const _Float16* __restrict__ XhT,
                                                const float* __restrict__ denom,
                                                float* __restrict__ out) {
  __shared__ _Float16 lds[2 * 32768];
  const int lin = blockIdx.x;
  const int ii = lin >> 3;
  const int b = (lin & 7) + 8 * (ii >> 4);
  const int tile = ii & 15;
  const int s0 = (tile >> 2) * 256;
  const int d0 = (tile & 3) * 256;
  const long base = (long)b * 1024;

  f32x4 acc[8][4];
  gemm256_run(P + (base + s0) * 1024, XhT + (base + d0) * 1024, lds, acc);

  const int tid = threadIdx.x;
  const int wave = tid >> 6, lane = tid & 63;
  const int wm = wave >> 2, wn = wave & 3;
  const int quad = lane >> 4, nl = lane & 15;
#pragma unroll
  for (int mi = 0; mi < 8; ++mi) {
#pragma unroll
    for (int r = 0; r < 4; ++r) {
      int s = s0 + wm * 128 + mi * 16 + quad * 4 + r;
      float inv = 1.0f / (denom[b * 1024 + s] + EPSF);
#pragma unroll
      for (int ni = 0; ni < 4; ++ni) {
        int d = d0 + wn * 64 + ni * 16 + nl;
        out[(base + s) * 1024 + d] = acc[mi][ni][r] * inv;
      }
    }
  }
}

// =================== fallback path (small ws) — unchanged 128^2 kernels =========
__global__ __launch_bounds__(256) void gemm1_k(const _Float16* __restrict__ Xh,
                                               const float* __restrict__ Wt,
                                               const float* __restrict__ bias,
                                               _Float16* __restrict__ XT) {
  __shared__ _Float16 As[128 * 32];
  __shared__ _Float16 Bs[128 * 32];
  const int tid = threadIdx.x;
  const int wave = tid >> 6, lane = tid & 63;
  const int wm = wave >> 1, wn = wave & 1;
  const int quad = lane >> 4, nl = lane & 15;
  const long m0 = (long)blockIdx.y * 128;
  const int n0 = blockIdx.x * 128;

  f32x4 acc[4][4];
  f32x4 zero = {0.f, 0.f, 0.f, 0.f};
#pragma unroll
  for (int i = 0; i < 4; ++i)
#pragma unroll
    for (int j = 0; j < 4; ++j) acc[i][j] = zero;

  const int crow = tid >> 2;
  const int ckc = (tid & 3) * 8;

  for (int k0 = 0; k0 < 1024; k0 += 32) {
#pragma unroll
    for (int it = 0; it < 2; ++it) {
      int c = it * 256 + tid;
      gload_lds16(Xh + (m0 + (c >> 2)) * 1024 + k0 + (c & 3) * 8,
                  &As[(it * 256 + wave * 64) * 8]);
      int row = it * 64 + crow;
      const float* sb = Wt + (long)(n0 + row) * 1024 + k0 + ckc;
      float4 b0 = *(const float4*)sb;
      float4 b1 = *(const float4*)(sb + 4);
      *(f16x8*)&Bs[row * 32 + ckc] = cvt8(b0, b1);
    }
    __syncthreads();
    f16x8 af[4], bf[4];
#pragma unroll
    for (int mi = 0; mi < 4; ++mi)
      af[mi] = *(const f16x8*)&As[(wm * 64 + mi * 16 + nl) * 32 + quad * 8];
#pragma unroll
    for (int ni = 0; ni < 4; ++ni)
      bf[ni] = *(const f16x8*)&Bs[(wn * 64 + ni * 16 + nl) * 32 + quad * 8];
#pragma unroll
    for (int mi = 0; mi < 4; ++mi)
#pragma unroll
      for (int ni = 0; ni < 4; ++ni)
        acc[mi][ni] = __builtin_amdgcn_mfma_f32_16x16x32_f16(af[mi], bf[ni], acc[mi][ni], 0, 0, 0);
    __syncthreads();
  }

#pragma unroll
  for (int mi = 0; mi < 4; ++mi) {
    long gm = m0 + wm * 64 + mi * 16 + quad * 4;
#pragma unroll
    for (int ni = 0; ni < 4; ++ni) {
      int gn = n0 + wn * 64 + ni * 16 + nl;
      float bv = bias[gn];
#pragma unroll
      for (int r = 0; r < 4; ++r)
        XT[(gm + r) * 1024 + gn] = (_Float16)(acc[mi][ni][r] + bv);
    }
  }
}

__global__ __launch_bounds__(256) void scores_f_k(const _Float16* __restrict__ XT,
                                                  const _Float16* __restrict__ Xh,
                                                  const float* __restrict__ opin,
                                                  _Float16* __restrict__ P,
                                                  float* __restrict__ denom) {
  __shared__ _Float16 As[128 * 32];
  __shared__ _Float16 Bs[128 * 32];
  const int tid = threadIdx.x;
  const int wave = tid >> 6, lane = tid & 63;
  const int wm = wave >> 1, wn = wave & 1;
  const int quad = lane >> 4, nl = lane & 15;
  const int b = blockIdx.z;
  const int s0 = blockIdx.y * 128;
  const int t0 = blockIdx.x * 128;
  const long base = (long)b * 1024;

  f32x4 acc[4][4];
  f32x4 zero = {0.f, 0.f, 0.f, 0.f};
#pragma unroll
  for (int i = 0; i < 4; ++i)
#pragma unroll
    for (int j = 0; j < 4; ++j) acc[i][j] = zero;

  for (int k0 = 0; k0 < 1024; k0 += 32) {
#pragma unroll
    for (int it = 0; it < 2; ++it) {
      int c = it * 256 + tid;
      gload_lds16(XT + (base + s0 + (c >> 2)) * 1024 + k0 + (c & 3) * 8,
                  &As[(it * 256 + wave * 64) * 8]);
      gload_lds16(Xh + (base + t0 + (c >> 2)) * 1024 + k0 + (c & 3) * 8,
                  &Bs[(it * 256 + wave * 64) * 8]);
    }
    __syncthreads();
    f16x8 af[4], bf[4];
#pragma unroll
    for (int mi = 0; mi < 4; ++mi)
      af[mi] = *(const f16x8*)&As[(wm * 64 + mi * 16 + nl) * 32 + quad * 8];
#pragma unroll
    for (int ni = 0; ni < 4; ++ni)
      bf[ni] = *(const f16x8*)&Bs[(wn * 64 + ni * 16 + nl) * 32 + quad * 8];
#pragma unroll
    for (int mi = 0; mi < 4; ++mi)
#pragma unroll
      for (int ni = 0; ni < 4; ++ni)
        acc[mi][ni] = __builtin_amdgcn_mfma_f32_16x16x32_f16(af[mi], bf[ni], acc[mi][ni], 0, 0, 0);
    __syncthreads();
  }

#pragma unroll
  for (int mi = 0; mi < 4; ++mi) {
#pragma unroll
    for (int r = 0; r < 4; ++r) {
      int s = s0 + wm * 64 + mi * 16 + quad * 4 + r;
      float opv = opin[b * 1024 + s];
      float rs = 0.f;
#pragma unroll
      for (int ni = 0; ni < 4; ++ni) {
        int t = t0 + wn * 64 + ni * 16 + nl;
        float loc = fabsf((float)(s - t));
        float arg = acc[mi][ni][r] * (1.0f / (loc + EPSF)) * opv;
        float th = 1.f - 2.f / (__expf(2.f * arg) + 1.f);
        float p = __expf(th);
        if (s == t) p = 0.f;
        P[(base + s) * 1024 + t] = (_Float16)p;
        rs += p;
      }
      rs += __shfl_xor(rs, 1);
      rs += __shfl_xor(rs, 2);
      rs += __shfl_xor(rs, 4);
      rs += __shfl_xor(rs, 8);
      if (nl == 0) atomicAdd(&denom[b * 1024 + s], rs);
    }
  }
}

__global__ __launch_bounds__(256) void pv_k(const _Float16* __restrict__ P,
                                            const float* __restrict__ X,
                                            const float* __restrict__ denom,
                                            float* __restrict__ out) {
  __shared__ _Float16 As[128 * 32];
  __shared__ _Float16 BsT[128 * 40];
  const int tid = threadIdx.x;
  const int wave = tid >> 6, lane = tid & 63;
  const int wm = wave >> 1, wn = wave & 1;
  const int quad = lane >> 4, nl = lane & 15;
  const int b = blockIdx.z;
  const int s0 = blockIdx.y * 128;
  const int d0 = blockIdx.x * 128;
  const long base = (long)b * 1024;

  const int dcol = tid & 127;
  const int tg = tid >> 7;

  f32x4 acc[4][4];
  f32x4 zero = {0.f, 0.f, 0.f, 0.f};
#pragma unroll
  for (int i = 0; i < 4; ++i)
#pragma unroll
    for (int j = 0; j < 4; ++j) acc[i][j] = zero;

  for (int k0 = 0; k0 < 1024; k0 += 32) {
#pragma unroll
    for (int it = 0; it < 2; ++it) {
      int c = it * 256 + tid;
      gload_lds16(P + (base + s0 + (c >> 2)) * 1024 + k0 + (c & 3) * 8,
                  &As[(it * 256 + wave * 64) * 8]);
    }
    {
      const float* xb = X + (base + k0 + tg * 16) * 1024 + d0 + dcol;
      float v[16];
#pragma unroll
      for (int j = 0; j < 16; ++j) v[j] = xb[j * 1024];
      f16x8 h0, h1;
#pragma unroll
      for (int j = 0; j < 8; ++j) { h0[j] = (_Float16)v[j]; h1[j] = (_Float16)v[8 + j]; }
      *(f16x8*)&BsT[dcol * 40 + tg * 16] = h0;
      *(f16x8*)&BsT[dcol * 40 + tg * 16 + 8] = h1;
    }
    __syncthreads();
    f16x8 af[4], bf[4];
#pragma unroll
    for (int mi = 0; mi < 4; ++mi)
      af[mi] = *(const f16x8*)&As[(wm * 64 + mi * 16 + nl) * 32 + quad * 8];
#pragma unroll
    for (int ni = 0; ni < 4; ++ni)
      bf[ni] = *(const f16x8*)&BsT[(wn * 64 + ni * 16 + nl) * 40 + quad * 8];
#pragma unroll
    for (int mi = 0; mi < 4; ++mi)
#pragma unroll
      for (int ni = 0; ni < 4; ++ni)
        acc[mi][ni] = __builtin_amdgcn_mfma_f32_16x16x32_f16(af[mi], bf[ni], acc[mi][ni], 0, 0, 0);
    __syncthreads();
  }

#pragma unroll
  for (int mi = 0; mi < 4; ++mi) {
#pragma unroll
    for (int r = 0; r < 4; ++r) {
      int s = s0 + wm * 64 + mi * 16 + quad * 4 + r;
      float inv = 1.0f / (denom[b * 1024 + s] + EPSF);
#pragma unroll
      for (int ni = 0; ni < 4; ++ni) {
        int d = d0 + wn * 64 + ni * 16 + nl;
        out[(base + s) * 1024 + d] = acc[mi][ni][r] * inv;
      }
    }
  }
}

extern "C" void kernel_launch(void* const* d_in, const int* in_sizes, int n_in,
                              void* d_out, int out_size, void* d_ws, size_t ws_size,
                              hipStream_t stream) {
  (void)in_sizes; (void)n_in; (void)out_size;
  const int B = 32, S = 1024;
  const int BS = B * S;

  const float* x     = (const float*)d_in[0];
  const float* W     = (const float*)d_in[1];
  const float* bias  = (const float*)d_in[2];
  const float* gold  = (const float*)d_in[3];
  const float* pred  = (const float*)d_in[4];
  const float* gprob = (const float*)d_in[5];

  const size_t P_BYTES  = (size_t)BS * 1024 * sizeof(_Float16);   // 64 MB
  const size_t XT_BYTES = P_BYTES;                                // 64 MB
  const size_t OPIN_B   = (size_t)BS * sizeof(float);             // 128 KB
  const size_t WH_B     = (size_t)1024 * 1024 * sizeof(_Float16); // 2 MB
  const size_t NEED_BIG = P_BYTES + XT_BYTES + 2 * OPIN_B + WH_B;

  char* ws = (char*)d_ws;
  _Float16* P = (_Float16*)ws;
  const bool big = ws_size >= NEED_BIG;

  // d_out double-duty: front 64MB = XT (fp16), back 64MB = Xh (fp16);
  // both dead before the PV kernel overwrites d_out with fp32 output.
  _Float16* XT = (_Float16*)d_out;
  _Float16* Xh = XT + (size_t)BS * 1024;
  float* out   = (float*)d_out;

  if (big) {
    _Float16* XhT = (_Float16*)(ws + P_BYTES);
    float* opin   = (float*)(ws + P_BYTES + XT_BYTES);
    float* denom  = opin + BS;
    _Float16* Wh  = (_Float16*)(ws + P_BYTES + XT_BYTES + 2 * OPIN_B);

    hipMemsetAsync(denom, 0, OPIN_B, stream);
    prep_opin_k<<<BS / 256, 256, 0, stream>>>(gold, pred, gprob, opin, BS);
    prep_h_k<<<(BS * 1024 / 8) / 256, 256, 0, stream>>>(x, Xh);
    prep_h_k<<<(1024 * 1024 / 8) / 256, 256, 0, stream>>>(W, Wh);
    prep_xt_k<<<dim3(16, 16, 32), 256, 0, stream>>>(x, XhT);
    gemm12_k<<<512, 512, 0, stream>>>(Xh, Wh, bias, XT);
    scores2_k<<<512, 512, 0, stream>>>(XT, Xh, opin, P, denom);
    pv2_k<<<512, 512, 0, stream>>>(P, XhT, denom, out);
  } else {
    float* opin  = (float*)(ws + P_BYTES);
    float* denom = opin + BS;

    hipMemsetAsync(denom, 0, OPIN_B, stream);
    prep_opin_k<<<BS / 256, 256, 0, stream>>>(gold, pred, gprob, opin, BS);
    prep_h_k<<<(BS * 1024 / 8) / 256, 256, 0, stream>>>(x, Xh);
    gemm1_k<<<dim3(8, 256), 256, 0, stream>>>(Xh, W, bias, XT);
    scores_f_k<<<dim3(8, 8, 32), 256, 0, stream>>>(XT, Xh, opin, P, denom);
    pv_k<<<dim3(8, 8, 32), 256, 0, stream>>>(P, x, denom, out);
  }
}

// Round 3
// 489.454 us; speedup vs baseline: 1.2159x; 1.0481x over previous
//
#include <hip/hip_runtime.h>

#define EPSF 1e-5f

typedef _Float16 f16x8 __attribute__((ext_vector_type(8)));
typedef float f32x4 __attribute__((ext_vector_type(4)));

__device__ __forceinline__ void gload_lds16(const _Float16* g, _Float16* l) {
  __builtin_amdgcn_global_load_lds(
      (const __attribute__((address_space(1))) unsigned int*)g,
      (__attribute__((address_space(3))) unsigned int*)l, 16, 0, 0);
}

__device__ __forceinline__ f16x8 cvt8(float4 a, float4 b) {
  f16x8 h;
  h[0] = (_Float16)a.x; h[1] = (_Float16)a.y; h[2] = (_Float16)a.z; h[3] = (_Float16)a.w;
  h[4] = (_Float16)b.x; h[5] = (_Float16)b.y; h[6] = (_Float16)b.z; h[7] = (_Float16)b.w;
  return h;
}

// fast reciprocal: v_rcp_f32 (~1 ulp; inf->0). absmax budget 9.8e-4 >> 1e-7.
__device__ __forceinline__ float frcp(float x) {
  float r;
  asm("v_rcp_f32 %0, %1" : "=v"(r) : "v"(x));
  return r;
}

// ==========================================================================
// 256x256 tile, K=1024 as 16 tiles of BK=64, 8 waves (2M x 4N), ring-2 LDS
// (2 x (A 32KB + B 32KB) = 128 KiB). 4-phase/tile interleave with counted
// vmcnt (never 0 in-loop). sched_barrier(0) pins {ds_read,STG} above the
// phase barrier and MFMA below the lgkmcnt(0) (rule #18 hygiene).
// LDS swizzle (T2, both-sides per rule #21): 128B rows, 16B chunk c at row r
// holds logical chunk c^(r&7); staged via inverse-permuted per-lane global
// source (gload_lds dest linear); ds_read applies the same XOR -> 2-way max.
// ==========================================================================
__device__ __forceinline__ void gemm256_run(const _Float16* __restrict__ Ag,
                                            const _Float16* __restrict__ Bg,
                                            _Float16* lds, f32x4 (&acc)[8][4]) {
  const int tid = threadIdx.x;
  const int wave = tid >> 6, lane = tid & 63;
  const int wm = wave >> 2, wn = wave & 3;
  const int quad = lane >> 4, nl = lane & 15;
  const int swz = nl & 7;  // = row&7 for all fragment rows this lane reads
  const long stg_off = (long)(wave * 8 + (lane >> 3)) * 1024 +
                       (((lane & 7) ^ (lane >> 3)) * 8);

#pragma unroll
  for (int i = 0; i < 8; ++i)
#pragma unroll
    for (int j = 0; j < 4; ++j) acc[i][j] = (f32x4){0.f, 0.f, 0.f, 0.f};

  f16x8 af[4], bf[4];

#define STG(G, T1, q, isB)                                                   \
  gload_lds16((G) + (long)(q) * 65536 + stg_off + (T1) * 64,                 \
              lds + (((T1) & 1) * 32768 + (isB) * 16384 + (q) * 4096 + wave * 512))
#define LDB4(bb, ksub)                                                       \
  {                                                                          \
    const _Float16* pB_ = lds + (bb) * 32768 + 16384 + (wn * 64 + nl) * 64 + \
                          ((((ksub) * 4 + quad) ^ swz) * 8);                 \
    _Pragma("unroll") for (int j_ = 0; j_ < 4; ++j_)                         \
        bf[j_] = *(const f16x8*)(pB_ + j_ * 1024);                           \
  }
#define LDA4(bb, mq, ksub)                                                   \
  {                                                                          \
    const _Float16* pA_ = lds + (bb) * 32768 +                               \
                          (wm * 128 + (mq) * 64 + nl) * 64 +                 \
                          ((((ksub) * 4 + quad) ^ swz) * 8);                 \
    _Pragma("unroll") for (int i_ = 0; i_ < 4; ++i_)                         \
        af[i_] = *(const f16x8*)(pA_ + i_ * 1024);                           \
  }
#define MFMA16(mq)                                                           \
  {                                                                          \
    __builtin_amdgcn_s_setprio(1);                                           \
    _Pragma("unroll") for (int i_ = 0; i_ < 4; ++i_)                         \
        _Pragma("unroll") for (int j_ = 0; j_ < 4; ++j_)                     \
            acc[(mq) * 4 + i_][j_] = __builtin_amdgcn_mfma_f32_16x16x32_f16( \
                af[i_], bf[j_], acc[(mq) * 4 + i_][j_], 0, 0, 0);            \
    __builtin_amdgcn_s_setprio(0);                                           \
  }
#define BAR __builtin_amdgcn_s_barrier()
#define SCHED0 __builtin_amdgcn_sched_barrier(0)
#define LGKM0 asm volatile("s_waitcnt lgkmcnt(0)" ::: "memory")
#define VMW2 asm volatile("s_waitcnt vmcnt(2)" ::: "memory")
#define VMW0 asm volatile("s_waitcnt vmcnt(0)" ::: "memory")

  // prologue: stage tile 0 in steady-state FIFO order
  STG(Bg, 0, 0, 1); STG(Bg, 0, 1, 1);
  STG(Ag, 0, 0, 0); STG(Ag, 0, 2, 0);
  STG(Bg, 0, 2, 1); STG(Bg, 0, 3, 1);
  STG(Ag, 0, 1, 0); STG(Ag, 0, 3, 0);
  VMW2;
  BAR;

#pragma unroll 2
  for (int T = 0; T < 15; ++T) {
    const int bb = T & 1;
    // p0: mq0,k0
    LDB4(bb, 0); LDA4(bb, 0, 0);
    STG(Bg, T + 1, 0, 1); STG(Bg, T + 1, 1, 1);
    SCHED0; BAR; LGKM0; SCHED0; MFMA16(0); VMW2; BAR;
    // p1: mq1,k0
    LDA4(bb, 1, 0);
    STG(Ag, T + 1, 0, 0); STG(Ag, T + 1, 2, 0);
    SCHED0; BAR; LGKM0; SCHED0; MFMA16(1); BAR;
    // p2: mq0,k1
    LDB4(bb, 1); LDA4(bb, 0, 1);
    STG(Bg, T + 1, 2, 1); STG(Bg, T + 1, 3, 1);
    SCHED0; BAR; LGKM0; SCHED0; MFMA16(0); BAR;
    // p3: mq1,k1
    LDA4(bb, 1, 1);
    STG(Ag, T + 1, 1, 0); STG(Ag, T + 1, 3, 0);
    SCHED0; BAR; LGKM0; SCHED0; MFMA16(1); VMW2; BAR;
  }
  {  // tile 15: no staging; drain
    LDB4(1, 0); LDA4(1, 0, 0);
    SCHED0; BAR; LGKM0; SCHED0; MFMA16(0); VMW0; BAR;
    LDA4(1, 1, 0);
    SCHED0; BAR; LGKM0; SCHED0; MFMA16(1); BAR;
    LDB4(1, 1); LDA4(1, 0, 1);
    SCHED0; BAR; LGKM0; SCHED0; MFMA16(0); BAR;
    LDA4(1, 1, 1);
    SCHED0; BAR; LGKM0; SCHED0; MFMA16(1); BAR;
  }
#undef VMW0
#undef VMW2
#undef LGKM0
#undef SCHED0
#undef BAR
#undef MFMA16
#undef LDA4
#undef LDB4
#undef STG
}

// ================= kernel 0a: opinion weights (fallback path only) ============
__global__ void prep_opin_k(const float* __restrict__ gold, const float* __restrict__ pred,
                            const float* __restrict__ gprob, float* __restrict__ opin, int n) {
  int i = blockIdx.x * 256 + threadIdx.x;
  if (i >= n) return;
  float gp = gprob[0];
  float go = gold[i * 5 + 1] + gold[i * 5 + 2];
  float po = pred[i * 5 + 3] + pred[i * 5 + 4];
  opin[i] = gp * go + (1.0f - gp) * po;
}

// ================= kernel 0b: fp32 -> fp16 copy (W->Wh; fallback x->Xh) =======
__global__ __launch_bounds__(256) void prep_h_k(const float* __restrict__ src,
                                                _Float16* __restrict__ dst) {
  long i = ((long)blockIdx.x * 256 + threadIdx.x) * 8;
  float4 a = *(const float4*)(src + i);
  float4 b = *(const float4*)(src + i + 4);
  *(f16x8*)(dst + i) = cvt8(a, b);
}

// ===== kernel 0c (fused): Xh = fp16(x), XhT[b][d][t] = fp16(x[b][t][d]) =======
// reads x once (256B/wave), writes both fp16 forms coalesced (128B/wave).
__global__ __launch_bounds__(256) void prep_x_k(const float* __restrict__ x,
                                                _Float16* __restrict__ Xh,
                                                _Float16* __restrict__ XhT) {
  __shared__ _Float16 T[64][66];  // ld=66 -> 2-way max on both sides
  const int d0 = blockIdx.x * 64, t0 = blockIdx.y * 64;
  const long base = (long)blockIdx.z * 1024;
  const int c = threadIdx.x & 63, tr = threadIdx.x >> 6;
#pragma unroll
  for (int k = 0; k < 16; ++k) {
    int t = k * 4 + tr;
    float v = x[(base + t0 + t) * 1024 + d0 + c];
    _Float16 h = (_Float16)v;
    Xh[(base + t0 + t) * 1024 + d0 + c] = h;
    T[t][c] = h;
  }
  __syncthreads();
#pragma unroll
  for (int k = 0; k < 16; ++k) {
    int d = k * 4 + tr;
    XhT[(base + d0 + d) * 1024 + t0 + c] = T[c][d];
  }
}

// ================= kernel 1 (big): XT = fp16(Xh @ Wh^T + b) ====================
__global__ __launch_bounds__(512, 2) void gemm12_k(const _Float16* __restrict__ Xh,
                                                   const _Float16* __restrict__ Wh,
                                                   const float* __restrict__ bias,
                                                   _Float16* __restrict__ XT) {
  __shared__ _Float16 lds[2 * 32768];
  const int lin = blockIdx.x;
  const int ii = lin >> 3;
  const int mt = (lin & 7) * 16 + (ii >> 2);
  const int nt = ii & 3;
  const long m0 = (long)mt * 256;
  const int n0 = nt * 256;

  f32x4 acc[8][4];
  gemm256_run(Xh + m0 * 1024, Wh + (long)n0 * 1024, lds, acc);

  const int tid = threadIdx.x;
  const int wave = tid >> 6, lane = tid & 63;
  const int wm = wave >> 2, wn = wave & 3;
  const int quad = lane >> 4, nl = lane & 15;
#pragma unroll
  for (int mi = 0; mi < 8; ++mi) {
    long gm = m0 + wm * 128 + mi * 16 + quad * 4;
#pragma unroll
    for (int ni = 0; ni < 4; ++ni) {
      int gn = n0 + wn * 64 + ni * 16 + nl;
      float bv = bias[gn];
#pragma unroll
      for (int r = 0; r < 4; ++r)
        XT[(gm + r) * 1024 + gn] = (_Float16)(acc[mi][ni][r] + bv);
    }
  }
}

// ======= kernel 2 (big): P = fp16(exp(tanh(XT@Xh^T * decay * opin))) ==========
// opin computed in-kernel (LDS); denom written as 16 race-free partial slices
// dpart[slice=tt*4+wn][b][s] (no memset, no atomics).
__global__ __launch_bounds__(512, 2) void scores2_k(const _Float16* __restrict__ XT,
                                                    const _Float16* __restrict__ Xh,
                                                    const float* __restrict__ gold,
                                                    const float* __restrict__ pred,
                                                    const float* __restrict__ gprob,
                                                    _Float16* __restrict__ P,
                                                    float* __restrict__ dpart) {
  __shared__ _Float16 lds[2 * 32768];
  const int lin = blockIdx.x;
  const int ii = lin >> 3;
  const int b = (lin & 7) + 8 * (ii >> 4);
  const int tile = ii & 15;
  const int s0 = (tile >> 2) * 256;
  const int t0 = (tile & 3) * 256;
  const long base = (long)b * 1024;

  f32x4 acc[8][4];
  gemm256_run(XT + (base + s0) * 1024, Xh + (base + t0) * 1024, lds, acc);
  // gemm ends with s_barrier -> LDS free for reuse

  const int tid = threadIdx.x;
  float* sop = (float*)lds;
  if (tid < 256) {
    int s = s0 + tid;
    float gp = gprob[0];
    long o = (base + s) * 5;
    float go = gold[o + 1] + gold[o + 2];
    float po = pred[o + 3] + pred[o + 4];
    sop[tid] = gp * go + (1.0f - gp) * po;
  }
  __syncthreads();

  const int wave = tid >> 6, lane = tid & 63;
  const int wm = wave >> 2, wn = wave & 3;
  const int quad = lane >> 4, nl = lane & 15;
  const int slice = (tile & 3) * 4 + wn;
#pragma unroll
  for (int mi = 0; mi < 8; ++mi) {
#pragma unroll
    for (int r = 0; r < 4; ++r) {
      int sl = wm * 128 + mi * 16 + quad * 4 + r;  // s - s0
      int s = s0 + sl;
      float opv = sop[sl];
      float rs = 0.f;
#pragma unroll
      for (int ni = 0; ni < 4; ++ni) {
        int tc = t0 + wn * 64 + ni * 16 + nl;
        float loc = fabsf((float)(s - tc));
        float arg = acc[mi][ni][r] * frcp(loc + EPSF) * opv;
        float th = 1.f - 2.f * frcp(__expf(2.f * arg) + 1.f);  // tanh(arg)
        float p = __expf(th);
        if (s == tc) p = 0.f;
        P[(base + s) * 1024 + tc] = (_Float16)p;
        rs += p;
      }
      rs += __shfl_xor(rs, 1);
      rs += __shfl_xor(rs, 2);
      rs += __shfl_xor(rs, 4);
      rs += __shfl_xor(rs, 8);
      if (nl == 0) dpart[(((long)slice * 32 + b) << 10) + s] = rs;
    }
  }
}

// ================= kernel 3 (big): out = (P @ XhT^T) / (denom + eps) ==========
__global__ __launch_bounds__(512, 2) void pv2_k(const _Float16* __restrict__ P,
                                                const _Float16* __restrict__ XhT,
                                                const float* __restrict__ dpart,
                                                float* __restrict__ out) {
  __shared__ _Float16 lds[2 * 32768];
  const int lin = blockIdx.x;
  const int ii = lin >> 3;
  const int b = (lin & 7) + 8 * (ii >> 4);
  const int tile = ii & 15;
  const int s0 = (tile >> 2) * 256;
  const int d0 = (tile & 3) * 256;
  const long base = (long)b * 1024;

  f32x4 acc[8][4];
  gemm256_run(P + (base + s0) * 1024, XhT + (base + d0) * 1024, lds, acc);

  const int tid = threadIdx.x;
  float* sden = (float*)lds;
  if (tid < 256) {
    float sum = 0.f;
#pragma unroll
    for (int k = 0; k < 16; ++k)
      sum += dpart[(((long)k * 32 + b) << 10) + s0 + tid];
    sden[tid] = frcp(sum + EPSF);
  }
  __syncthreads();

  const int wave = tid >> 6, lane = tid & 63;
  const int wm = wave >> 2, wn = wave & 3;
  const int quad = lane >> 4, nl = lane & 15;
#pragma unroll
  for (int mi = 0; mi < 8; ++mi) {
#pragma unroll
    for (int r = 0; r < 4; ++r) {
      int sl = wm * 128 + mi * 16 + quad * 4 + r;
      int s = s0 + sl;
      float inv = sden[sl];
#pragma unroll
      for (int ni = 0; ni < 4; ++ni) {
        int d = d0 + wn * 64 + ni * 16 + nl;
        out[(base + s) * 1024 + d] = acc[mi][ni][r] * inv;
      }
    }
  }
}

// =================== fallback path (small ws) — unchanged 128^2 kernels =========
__global__ __launch_bounds__(256) void gemm1_k(const _Float16* __restrict__ Xh,
                                               const float* __restrict__ Wt,
                                               const float* __restrict__ bias,
                                               _Float16* __restrict__ XT) {
  __shared__ _Float16 As[128 * 32];
  __shared__ _Float16 Bs[128 * 32];
  const int tid = threadIdx.x;
  const int wave = tid >> 6, lane = tid & 63;
  const int wm = wave >> 1, wn = wave & 1;
  const int quad = lane >> 4, nl = lane & 15;
  const long m0 = (long)blockIdx.y * 128;
  const int n0 = blockIdx.x * 128;

  f32x4 acc[4][4];
  f32x4 zero = {0.f, 0.f, 0.f, 0.f};
#pragma unroll
  for (int i = 0; i < 4; ++i)
#pragma unroll
    for (int j = 0; j < 4; ++j) acc[i][j] = zero;

  const int crow = tid >> 2;
  const int ckc = (tid & 3) * 8;

  for (int k0 = 0; k0 < 1024; k0 += 32) {
#pragma unroll
    for (int it = 0; it < 2; ++it) {
      int c = it * 256 + tid;
      gload_lds16(Xh + (m0 + (c >> 2)) * 1024 + k0 + (c & 3) * 8,
                  &As[(it * 256 + wave * 64) * 8]);
      int row = it * 64 + crow;
      const float* sb = Wt + (long)(n0 + row) * 1024 + k0 + ckc;
      float4 b0 = *(const float4*)sb;
      float4 b1 = *(const float4*)(sb + 4);
      *(f16x8*)&Bs[row * 32 + ckc] = cvt8(b0, b1);
    }
    __syncthreads();
    f16x8 af[4], bf[4];
#pragma unroll
    for (int mi = 0; mi < 4; ++mi)
      af[mi] = *(const f16x8*)&As[(wm * 64 + mi * 16 + nl) * 32 + quad * 8];
#pragma unroll
    for (int ni = 0; ni < 4; ++ni)
      bf[ni] = *(const f16x8*)&Bs[(wn * 64 + ni * 16 + nl) * 32 + quad * 8];
#pragma unroll
    for (int mi = 0; mi < 4; ++mi)
#pragma unroll
      for (int ni = 0; ni < 4; ++ni)
        acc[mi][ni] = __builtin_amdgcn_mfma_f32_16x16x32_f16(af[mi], bf[ni], acc[mi][ni], 0, 0, 0);
    __syncthreads();
  }

#pragma unroll
  for (int mi = 0; mi < 4; ++mi) {
    long gm = m0 + wm * 64 + mi * 16 + quad * 4;
#pragma unroll
    for (int ni = 0; ni < 4; ++ni) {
      int gn = n0 + wn * 64 + ni * 16 + nl;
      float bv = bias[gn];
#pragma unroll
      for (int r = 0; r < 4; ++r)
        XT[(gm + r) * 1024 + gn] = (_Float16)(acc[mi][ni][r] + bv);
    }
  }
}

__global__ __launch_bounds__(256) void scores_f_k(const _Float16* __restrict__ XT,
                                                  const _Float16* __restrict__ Xh,
                                                  const float* __restrict__ opin,
                                                  _Float16* __restrict__ P,
                                                  float* __restrict__ denom) {
  __shared__ _Float16 As[128 * 32];
  __shared__ _Float16 Bs[128 * 32];
  const int tid = threadIdx.x;
  const int wave = tid >> 6, lane = tid & 63;
  const int wm = wave >> 1, wn = wave & 1;
  const int quad = lane >> 4, nl = lane & 15;
  const int b = blockIdx.z;
  const int s0 = blockIdx.y * 128;
  const int t0 = blockIdx.x * 128;
  const long base = (long)b * 1024;

  f32x4 acc[4][4];
  f32x4 zero = {0.f, 0.f, 0.f, 0.f};
#pragma unroll
  for (int i = 0; i < 4; ++i)
#pragma unroll
    for (int j = 0; j < 4; ++j) acc[i][j] = zero;

  for (int k0 = 0; k0 < 1024; k0 += 32) {
#pragma unroll
    for (int it = 0; it < 2; ++it) {
      int c = it * 256 + tid;
      gload_lds16(XT + (base + s0 + (c >> 2)) * 1024 + k0 + (c & 3) * 8,
                  &As[(it * 256 + wave * 64) * 8]);
      gload_lds16(Xh + (base + t0 + (c >> 2)) * 1024 + k0 + (c & 3) * 8,
                  &Bs[(it * 256 + wave * 64) * 8]);
    }
    __syncthreads();
    f16x8 af[4], bf[4];
#pragma unroll
    for (int mi = 0; mi < 4; ++mi)
      af[mi] = *(const f16x8*)&As[(wm * 64 + mi * 16 + nl) * 32 + quad * 8];
#pragma unroll
    for (int ni = 0; ni < 4; ++ni)
      bf[ni] = *(const f16x8*)&Bs[(wn * 64 + ni * 16 + nl) * 32 + quad * 8];
#pragma unroll
    for (int mi = 0; mi < 4; ++mi)
#pragma unroll
      for (int ni = 0; ni < 4; ++ni)
        acc[mi][ni] = __builtin_amdgcn_mfma_f32_16x16x32_f16(af[mi], bf[ni], acc[mi][ni], 0, 0, 0);
    __syncthreads();
  }

#pragma unroll
  for (int mi = 0; mi < 4; ++mi) {
#pragma unroll
    for (int r = 0; r < 4; ++r) {
      int s = s0 + wm * 64 + mi * 16 + quad * 4 + r;
      float opv = opin[b * 1024 + s];
      float rs = 0.f;
#pragma unroll
      for (int ni = 0; ni < 4; ++ni) {
        int t = t0 + wn * 64 + ni * 16 + nl;
        float loc = fabsf((float)(s - t));
        float arg = acc[mi][ni][r] * (1.0f / (loc + EPSF)) * opv;
        float th = 1.f - 2.f / (__expf(2.f * arg) + 1.f);
        float p = __expf(th);
        if (s == t) p = 0.f;
        P[(base + s) * 1024 + t] = (_Float16)p;
        rs += p;
      }
      rs += __shfl_xor(rs, 1);
      rs += __shfl_xor(rs, 2);
      rs += __shfl_xor(rs, 4);
      rs += __shfl_xor(rs, 8);
      if (nl == 0) atomicAdd(&denom[b * 1024 + s], rs);
    }
  }
}

__global__ __launch_bounds__(256) void pv_k(const _Float16* __restrict__ P,
                                            const float* __restrict__ X,
                                            const float* __restrict__ denom,
                                            float* __restrict__ out) {
  __shared__ _Float16 As[128 * 32];
  __shared__ _Float16 BsT[128 * 40];
  const int tid = threadIdx.x;
  const int wave = tid >> 6, lane = tid & 63;
  const int wm = wave >> 1, wn = wave & 1;
  const int quad = lane >> 4, nl = lane & 15;
  const int b = blockIdx.z;
  const int s0 = blockIdx.y * 128;
  const int d0 = blockIdx.x * 128;
  const long base = (long)b * 1024;

  const int dcol = tid & 127;
  const int tg = tid >> 7;

  f32x4 acc[4][4];
  f32x4 zero = {0.f, 0.f, 0.f, 0.f};
#pragma unroll
  for (int i = 0; i < 4; ++i)
#pragma unroll
    for (int j = 0; j < 4; ++j) acc[i][j] = zero;

  for (int k0 = 0; k0 < 1024; k0 += 32) {
#pragma unroll
    for (int it = 0; it < 2; ++it) {
      int c = it * 256 + tid;
      gload_lds16(P + (base + s0 + (c >> 2)) * 1024 + k0 + (c & 3) * 8,
                  &As[(it * 256 + wave * 64) * 8]);
    }
    {
      const float* xb = X + (base + k0 + tg * 16) * 1024 + d0 + dcol;
      float v[16];
#pragma unroll
      for (int j = 0; j < 16; ++j) v[j] = xb[j * 1024];
      f16x8 h0, h1;
#pragma unroll
      for (int j = 0; j < 8; ++j) { h0[j] = (_Float16)v[j]; h1[j] = (_Float16)v[8 + j]; }
      *(f16x8*)&BsT[dcol * 40 + tg * 16] = h0;
      *(f16x8*)&BsT[dcol * 40 + tg * 16 + 8] = h1;
    }
    __syncthreads();
    f16x8 af[4], bf[4];
#pragma unroll
    for (int mi = 0; mi < 4; ++mi)
      af[mi] = *(const f16x8*)&As[(wm * 64 + mi * 16 + nl) * 32 + quad * 8];
#pragma unroll
    for (int ni = 0; ni < 4; ++ni)
      bf[ni] = *(const f16x8*)&BsT[(wn * 64 + ni * 16 + nl) * 40 + quad * 8];
#pragma unroll
    for (int mi = 0; mi < 4; ++mi)
#pragma unroll
      for (int ni = 0; ni < 4; ++ni)
        acc[mi][ni] = __builtin_amdgcn_mfma_f32_16x16x32_f16(af[mi], bf[ni], acc[mi][ni], 0, 0, 0);
    __syncthreads();
  }

#pragma unroll
  for (int mi = 0; mi < 4; ++mi) {
#pragma unroll
    for (int r = 0; r < 4; ++r) {
      int s = s0 + wm * 64 + mi * 16 + quad * 4 + r;
      float inv = 1.0f / (denom[b * 1024 + s] + EPSF);
#pragma unroll
      for (int ni = 0; ni < 4; ++ni) {
        int d = d0 + wn * 64 + ni * 16 + nl;
        out[(base + s) * 1024 + d] = acc[mi][ni][r] * inv;
      }
    }
  }
}

extern "C" void kernel_launch(void* const* d_in, const int* in_sizes, int n_in,
                              void* d_out, int out_size, void* d_ws, size_t ws_size,
                              hipStream_t stream) {
  (void)in_sizes; (void)n_in; (void)out_size;
  const int B = 32, S = 1024;
  const int BS = B * S;

  const float* x     = (const float*)d_in[0];
  const float* W     = (const float*)d_in[1];
  const float* bias  = (const float*)d_in[2];
  const float* gold  = (const float*)d_in[3];
  const float* pred  = (const float*)d_in[4];
  const float* gprob = (const float*)d_in[5];

  const size_t P_BYTES  = (size_t)BS * 1024 * sizeof(_Float16);   // 64 MB
  const size_t XT_BYTES = P_BYTES;                                // 64 MB
  const size_t DP_B     = (size_t)16 * BS * sizeof(float);        // 2 MB
  const size_t WH_B     = (size_t)1024 * 1024 * sizeof(_Float16); // 2 MB
  const size_t OPIN_B   = (size_t)BS * sizeof(float);             // 128 KB
  const size_t NEED_BIG = P_BYTES + XT_BYTES + DP_B + WH_B;

  char* ws = (char*)d_ws;
  _Float16* P = (_Float16*)ws;
  const bool big = ws_size >= NEED_BIG;

  // d_out double-duty: front 64MB = XT (fp16), back 64MB = Xh (fp16);
  // both dead before the PV kernel overwrites d_out with fp32 output.
  _Float16* XT = (_Float16*)d_out;
  _Float16* Xh = XT + (size_t)BS * 1024;
  float* out   = (float*)d_out;

  if (big) {
    _Float16* XhT = (_Float16*)(ws + P_BYTES);
    float* dpart  = (float*)(ws + P_BYTES + XT_BYTES);
    _Float16* Wh  = (_Float16*)(ws + P_BYTES + XT_BYTES + DP_B);

    prep_x_k<<<dim3(16, 16, 32), 256, 0, stream>>>(x, Xh, XhT);
    prep_h_k<<<(1024 * 1024 / 8) / 256, 256, 0, stream>>>(W, Wh);
    gemm12_k<<<512, 512, 0, stream>>>(Xh, Wh, bias, XT);
    scores2_k<<<512, 512, 0, stream>>>(XT, Xh, gold, pred, gprob, P, dpart);
    pv2_k<<<512, 512, 0, stream>>>(P, XhT, dpart, out);
  } else {
    float* opin  = (float*)(ws + P_BYTES);
    float* denom = opin + BS;

    hipMemsetAsync(denom, 0, OPIN_B, stream);
    prep_opin_k<<<BS / 256, 256, 0, stream>>>(gold, pred, gprob, opin, BS);
    prep_h_k<<<(BS * 1024 / 8) / 256, 256, 0, stream>>>(x, Xh);
    gemm1_k<<<dim3(8, 256), 256, 0, stream>>>(Xh, W, bias, XT);
    scores_f_k<<<dim3(8, 8, 32), 256, 0, stream>>>(XT, Xh, opin, P, denom);
    pv_k<<<dim3(8, 8, 32), 256, 0, stream>>>(P, x, denom, out);
  }
}

// Round 4
// 480.908 us; speedup vs baseline: 1.2375x; 1.0178x over previous
//
#include <hip/hip_runtime.h>

#define EPSF 1e-5f

typedef _Float16 f16x8 __attribute__((ext_vector_type(8)));
typedef float f32x4 __attribute__((ext_vector_type(4)));

__device__ __forceinline__ void gload_lds16(const _Float16* g, _Float16* l) {
  __builtin_amdgcn_global_load_lds(
      (const __attribute__((address_space(1))) unsigned int*)g,
      (__attribute__((address_space(3))) unsigned int*)l, 16, 0, 0);
}

__device__ __forceinline__ f16x8 cvt8(float4 a, float4 b) {
  f16x8 h;
  h[0] = (_Float16)a.x; h[1] = (_Float16)a.y; h[2] = (_Float16)a.z; h[3] = (_Float16)a.w;
  h[4] = (_Float16)b.x; h[5] = (_Float16)b.y; h[6] = (_Float16)b.z; h[7] = (_Float16)b.w;
  return h;
}

// fast reciprocal: v_rcp_f32 (~1 ulp; inf->0). absmax budget 9.8e-4 >> 1e-7.
__device__ __forceinline__ float frcp(float x) {
  float r;
  asm("v_rcp_f32 %0, %1" : "=v"(r) : "v"(x));
  return r;
}

// ==========================================================================
// 256x256 tile, K=1024 as 32 tiles of BK=32, 8 waves (2M x 4N), ring-4 LDS
// (4 x (A 16KB + B 16KB) = 128 KiB). Deep pipeline: stage tile T+3 during
// tile T; single counted vmcnt(8) per tile -> the waited-on loads were
// issued 2 tiles (4 phases, >2500 cy) earlier, so HBM/L2 latency is fully
// hidden (R3's ring-2 waited on loads 1-3 phases old = latency-sized stall).
// 2 phases/tile: { ds_read frags | stage 2 loads of T+3 | SCHED0 | BAR |
//                  LGKM0 | SCHED0 | setprio(1) 16 MFMA setprio(0) | [VMW] | BAR }
// LDS swizzle (64B rows, 4x16B chunks): position p holds logical chunk
// p^((row>>1)&3); staged via pre-swizzled per-lane GLOBAL source (gload_lds
// dest linear, rule #21); ds_read applies same XOR. Within each 16-lane
// quarter-wave: 8 (parity,pos) buckets x 2 lanes = 2-way max (free, m136).
// ==========================================================================
__device__ __forceinline__ void gemm256_run(const _Float16* __restrict__ Ag,
                                            const _Float16* __restrict__ Bg,
                                            _Float16* lds, f32x4 (&acc)[8][4]) {
  const int tid = threadIdx.x;
  const int wave = tid >> 6, lane = tid & 63;
  const int wm = wave >> 2, wn = wave & 3;
  const int quad = lane >> 4, nl = lane & 15;
  const int swz = (nl >> 1) & 3;  // = (row>>1)&3 for all fragment rows of this lane
  // staging: load (half h) covers 128 rows x 4 chunk-positions; thread t:
  // row_local = t>>2, pos = t&3, logical chunk c = (t&3)^((t>>3)&3).
  const long stg_off = (long)(tid >> 2) * 1024 + (((tid & 3) ^ ((tid >> 3) & 3)) * 8);

#pragma unroll
  for (int i = 0; i < 8; ++i)
#pragma unroll
    for (int j = 0; j < 4; ++j) acc[i][j] = (f32x4){0.f, 0.f, 0.f, 0.f};

  f16x8 af[4], bf[4];

#define STG(G, Tidx, h, isB, SBUF)                                           \
  gload_lds16((G) + (long)(h) * 131072 + stg_off + (Tidx) * 32,              \
              lds + (SBUF) * 16384 + (isB) * 8192 + (h) * 4096 + wave * 512)
#define LDB4(BUF)                                                            \
  {                                                                          \
    const _Float16* pB_ = lds + (BUF) * 16384 + 8192 +                       \
                          (wn * 64 + nl) * 32 + ((quad ^ swz) * 8);          \
    _Pragma("unroll") for (int j_ = 0; j_ < 4; ++j_)                         \
        bf[j_] = *(const f16x8*)(pB_ + j_ * 512);                            \
  }
#define LDA4(BUF, mq)                                                        \
  {                                                                          \
    const _Float16* pA_ = lds + (BUF) * 16384 +                              \
                          (wm * 128 + (mq) * 64 + nl) * 32 + ((quad ^ swz) * 8); \
    _Pragma("unroll") for (int i_ = 0; i_ < 4; ++i_)                         \
        af[i_] = *(const f16x8*)(pA_ + i_ * 512);                            \
  }
#define MFMA16(mq)                                                           \
  {                                                                          \
    __builtin_amdgcn_s_setprio(1);                                           \
    _Pragma("unroll") for (int i_ = 0; i_ < 4; ++i_)                         \
        _Pragma("unroll") for (int j_ = 0; j_ < 4; ++j_)                     \
            acc[(mq) * 4 + i_][j_] = __builtin_amdgcn_mfma_f32_16x16x32_f16( \
                af[i_], bf[j_], acc[(mq) * 4 + i_][j_], 0, 0, 0);            \
    __builtin_amdgcn_s_setprio(0);                                           \
  }
#define BAR __builtin_amdgcn_s_barrier()
#define SCHED0 __builtin_amdgcn_sched_barrier(0)
#define LGKM0 asm volatile("s_waitcnt lgkmcnt(0)" ::: "memory")
#define VMW8 asm volatile("s_waitcnt vmcnt(8)" ::: "memory")
#define VMW4 asm volatile("s_waitcnt vmcnt(4)" ::: "memory")
#define VMW0 asm volatile("s_waitcnt vmcnt(0)" ::: "memory")
#define VMNONE
// one tile = 2 phases; DOSTG stages tile T+3 into SBUF=(T+3)&3 (compile-time)
#define TILE(T, BUF, SBUF, DOSTG, VW)                                        \
  {                                                                          \
    LDB4(BUF); LDA4(BUF, 0);                                                 \
    if (DOSTG) { STG(Bg, (T) + 3, 0, 1, SBUF); STG(Bg, (T) + 3, 1, 1, SBUF); } \
    SCHED0; BAR; LGKM0; SCHED0; MFMA16(0); BAR;                              \
    LDA4(BUF, 1);                                                            \
    if (DOSTG) { STG(Ag, (T) + 3, 0, 0, SBUF); STG(Ag, (T) + 3, 1, 0, SBUF); } \
    SCHED0; BAR; LGKM0; SCHED0; MFMA16(1); VW; BAR;                          \
  }

  // prologue: stage tiles 0,1,2 (12 loads); vmcnt(8) -> tile0's 4 landed
  STG(Bg, 0, 0, 1, 0); STG(Bg, 0, 1, 1, 0); STG(Ag, 0, 0, 0, 0); STG(Ag, 0, 1, 0, 0);
  STG(Bg, 1, 0, 1, 1); STG(Bg, 1, 1, 1, 1); STG(Ag, 1, 0, 0, 1); STG(Ag, 1, 1, 0, 1);
  STG(Bg, 2, 0, 1, 2); STG(Bg, 2, 1, 1, 2); STG(Ag, 2, 0, 0, 2); STG(Ag, 2, 1, 0, 2);
  VMW8;
  BAR;

  for (int TT = 0; TT < 28; TT += 4) {
    TILE(TT + 0, 0, 3, true, VMW8);
    TILE(TT + 1, 1, 0, true, VMW8);
    TILE(TT + 2, 2, 1, true, VMW8);
    TILE(TT + 3, 3, 2, true, VMW8);
  }
  TILE(28, 0, 3, true, VMW8);   // stages tile 31 into buf 3
  TILE(29, 1, 0, false, VMW4);  // drain: tile 30 lands
  TILE(30, 2, 0, false, VMW0);  // drain: tile 31 lands
  TILE(31, 3, 0, false, VMNONE);

#undef TILE
#undef VMNONE
#undef VMW0
#undef VMW4
#undef VMW8
#undef LGKM0
#undef SCHED0
#undef BAR
#undef MFMA16
#undef LDA4
#undef LDB4
#undef STG
}

// ================= kernel 0a: opinion weights (fallback path only) ============
__global__ void prep_opin_k(const float* __restrict__ gold, const float* __restrict__ pred,
                            const float* __restrict__ gprob, float* __restrict__ opin, int n) {
  int i = blockIdx.x * 256 + threadIdx.x;
  if (i >= n) return;
  float gp = gprob[0];
  float go = gold[i * 5 + 1] + gold[i * 5 + 2];
  float po = pred[i * 5 + 3] + pred[i * 5 + 4];
  opin[i] = gp * go + (1.0f - gp) * po;
}

// ================= kernel 0b: fp32 -> fp16 copy (W->Wh; fallback x->Xh) =======
__global__ __launch_bounds__(256) void prep_h_k(const float* __restrict__ src,
                                                _Float16* __restrict__ dst) {
  long i = ((long)blockIdx.x * 256 + threadIdx.x) * 8;
  float4 a = *(const float4*)(src + i);
  float4 b = *(const float4*)(src + i + 4);
  *(f16x8*)(dst + i) = cvt8(a, b);
}

// ===== kernel 0c (fused): Xh = fp16(x), XhT[b][d][t] = fp16(x[b][t][d]) =======
__global__ __launch_bounds__(256) void prep_x_k(const float* __restrict__ x,
                                                _Float16* __restrict__ Xh,
                                                _Float16* __restrict__ XhT) {
  __shared__ _Float16 T[64][66];  // ld=66 -> 2-way max on both sides
  const int d0 = blockIdx.x * 64, t0 = blockIdx.y * 64;
  const long base = (long)blockIdx.z * 1024;
  const int c = threadIdx.x & 63, tr = threadIdx.x >> 6;
#pragma unroll
  for (int k = 0; k < 16; ++k) {
    int t = k * 4 + tr;
    float v = x[(base + t0 + t) * 1024 + d0 + c];
    _Float16 h = (_Float16)v;
    Xh[(base + t0 + t) * 1024 + d0 + c] = h;
    T[t][c] = h;
  }
  __syncthreads();
#pragma unroll
  for (int k = 0; k < 16; ++k) {
    int d = k * 4 + tr;
    XhT[(base + d0 + d) * 1024 + t0 + c] = T[c][d];
  }
}

// ================= kernel 1 (big): XT = fp16(Xh @ Wh^T + b) ====================
__global__ __launch_bounds__(512, 2) void gemm12_k(const _Float16* __restrict__ Xh,
                                                   const _Float16* __restrict__ Wh,
                                                   const float* __restrict__ bias,
                                                   _Float16* __restrict__ XT) {
  __shared__ _Float16 lds[4 * 16384];
  const int lin = blockIdx.x;
  const int ii = lin >> 3;
  const int mt = (lin & 7) * 16 + (ii >> 2);
  const int nt = ii & 3;
  const long m0 = (long)mt * 256;
  const int n0 = nt * 256;

  f32x4 acc[8][4];
  gemm256_run(Xh + m0 * 1024, Wh + (long)n0 * 1024, lds, acc);

  const int tid = threadIdx.x;
  const int wave = tid >> 6, lane = tid & 63;
  const int wm = wave >> 2, wn = wave & 3;
  const int quad = lane >> 4, nl = lane & 15;
#pragma unroll
  for (int mi = 0; mi < 8; ++mi) {
    long gm = m0 + wm * 128 + mi * 16 + quad * 4;
#pragma unroll
    for (int ni = 0; ni < 4; ++ni) {
      int gn = n0 + wn * 64 + ni * 16 + nl;
      float bv = bias[gn];
#pragma unroll
      for (int r = 0; r < 4; ++r)
        XT[(gm + r) * 1024 + gn] = (_Float16)(acc[mi][ni][r] + bv);
    }
  }
}

// ======= kernel 2 (big): P = fp16(exp(tanh(XT@Xh^T * decay * opin))) ==========
__global__ __launch_bounds__(512, 2) void scores2_k(const _Float16* __restrict__ XT,
                                                    const _Float16* __restrict__ Xh,
                                                    const float* __restrict__ gold,
                                                    const float* __restrict__ pred,
                                                    const float* __restrict__ gprob,
                                                    _Float16* __restrict__ P,
                                                    float* __restrict__ dpart) {
  __shared__ _Float16 lds[4 * 16384];
  const int lin = blockIdx.x;
  const int ii = lin >> 3;
  const int b = (lin & 7) + 8 * (ii >> 4);
  const int tile = ii & 15;
  const int s0 = (tile >> 2) * 256;
  const int t0 = (tile & 3) * 256;
  const long base = (long)b * 1024;

  f32x4 acc[8][4];
  gemm256_run(XT + (base + s0) * 1024, Xh + (base + t0) * 1024, lds, acc);
  // gemm ends with s_barrier -> LDS free for reuse

  const int tid = threadIdx.x;
  float* sop = (float*)lds;
  if (tid < 256) {
    int s = s0 + tid;
    float gp = gprob[0];
    long o = (base + s) * 5;
    float go = gold[o + 1] + gold[o + 2];
    float po = pred[o + 3] + pred[o + 4];
    sop[tid] = gp * go + (1.0f - gp) * po;
  }
  __syncthreads();

  const int wave = tid >> 6, lane = tid & 63;
  const int wm = wave >> 2, wn = wave & 3;
  const int quad = lane >> 4, nl = lane & 15;
  const int slice = (tile & 3) * 4 + wn;
#pragma unroll
  for (int mi = 0; mi < 8; ++mi) {
#pragma unroll
    for (int r = 0; r < 4; ++r) {
      int sl = wm * 128 + mi * 16 + quad * 4 + r;  // s - s0
      int s = s0 + sl;
      float opv = sop[sl];
      float rs = 0.f;
#pragma unroll
      for (int ni = 0; ni < 4; ++ni) {
        int tc = t0 + wn * 64 + ni * 16 + nl;
        float loc = fabsf((float)(s - tc));
        float arg = acc[mi][ni][r] * frcp(loc + EPSF) * opv;
        float th = 1.f - 2.f * frcp(__expf(2.f * arg) + 1.f);  // tanh(arg)
        float p = __expf(th);
        if (s == tc) p = 0.f;
        P[(base + s) * 1024 + tc] = (_Float16)p;
        rs += p;
      }
      rs += __shfl_xor(rs, 1);
      rs += __shfl_xor(rs, 2);
      rs += __shfl_xor(rs, 4);
      rs += __shfl_xor(rs, 8);
      if (nl == 0) dpart[(((long)slice * 32 + b) << 10) + s] = rs;
    }
  }
}

// ================= kernel 3 (big): out = (P @ XhT^T) / (denom + eps) ==========
__global__ __launch_bounds__(512, 2) void pv2_k(const _Float16* __restrict__ P,
                                                const _Float16* __restrict__ XhT,
                                                const float* __restrict__ dpart,
                                                float* __restrict__ out) {
  __shared__ _Float16 lds[4 * 16384];
  const int lin = blockIdx.x;
  const int ii = lin >> 3;
  const int b = (lin & 7) + 8 * (ii >> 4);
  const int tile = ii & 15;
  const int s0 = (tile >> 2) * 256;
  const int d0 = (tile & 3) * 256;
  const long base = (long)b * 1024;

  f32x4 acc[8][4];
  gemm256_run(P + (base + s0) * 1024, XhT + (base + d0) * 1024, lds, acc);

  const int tid = threadIdx.x;
  float* sden = (float*)lds;
  if (tid < 256) {
    float sum = 0.f;
#pragma unroll
    for (int k = 0; k < 16; ++k)
      sum += dpart[(((long)k * 32 + b) << 10) + s0 + tid];
    sden[tid] = frcp(sum + EPSF);
  }
  __syncthreads();

  const int wave = tid >> 6, lane = tid & 63;
  const int wm = wave >> 2, wn = wave & 3;
  const int quad = lane >> 4, nl = lane & 15;
#pragma unroll
  for (int mi = 0; mi < 8; ++mi) {
#pragma unroll
    for (int r = 0; r < 4; ++r) {
      int sl = wm * 128 + mi * 16 + quad * 4 + r;
      int s = s0 + sl;
      float inv = sden[sl];
#pragma unroll
      for (int ni = 0; ni < 4; ++ni) {
        int d = d0 + wn * 64 + ni * 16 + nl;
        out[(base + s) * 1024 + d] = acc[mi][ni][r] * inv;
      }
    }
  }
}

// =================== fallback path (small ws) — unchanged 128^2 kernels =========
__global__ __launch_bounds__(256) void gemm1_k(const _Float16* __restrict__ Xh,
                                               const float* __restrict__ Wt,
                                               const float* __restrict__ bias,
                                               _Float16* __restrict__ XT) {
  __shared__ _Float16 As[128 * 32];
  __shared__ _Float16 Bs[128 * 32];
  const int tid = threadIdx.x;
  const int wave = tid >> 6, lane = tid & 63;
  const int wm = wave >> 1, wn = wave & 1;
  const int quad = lane >> 4, nl = lane & 15;
  const long m0 = (long)blockIdx.y * 128;
  const int n0 = blockIdx.x * 128;

  f32x4 acc[4][4];
  f32x4 zero = {0.f, 0.f, 0.f, 0.f};
#pragma unroll
  for (int i = 0; i < 4; ++i)
#pragma unroll
    for (int j = 0; j < 4; ++j) acc[i][j] = zero;

  const int crow = tid >> 2;
  const int ckc = (tid & 3) * 8;

  for (int k0 = 0; k0 < 1024; k0 += 32) {
#pragma unroll
    for (int it = 0; it < 2; ++it) {
      int c = it * 256 + tid;
      gload_lds16(Xh + (m0 + (c >> 2)) * 1024 + k0 + (c & 3) * 8,
                  &As[(it * 256 + wave * 64) * 8]);
      int row = it * 64 + crow;
      const float* sb = Wt + (long)(n0 + row) * 1024 + k0 + ckc;
      float4 b0 = *(const float4*)sb;
      float4 b1 = *(const float4*)(sb + 4);
      *(f16x8*)&Bs[row * 32 + ckc] = cvt8(b0, b1);
    }
    __syncthreads();
    f16x8 af[4], bf[4];
#pragma unroll
    for (int mi = 0; mi < 4; ++mi)
      af[mi] = *(const f16x8*)&As[(wm * 64 + mi * 16 + nl) * 32 + quad * 8];
#pragma unroll
    for (int ni = 0; ni < 4; ++ni)
      bf[ni] = *(const f16x8*)&Bs[(wn * 64 + ni * 16 + nl) * 32 + quad * 8];
#pragma unroll
    for (int mi = 0; mi < 4; ++mi)
#pragma unroll
      for (int ni = 0; ni < 4; ++ni)
        acc[mi][ni] = __builtin_amdgcn_mfma_f32_16x16x32_f16(af[mi], bf[ni], acc[mi][ni], 0, 0, 0);
    __syncthreads();
  }

#pragma unroll
  for (int mi = 0; mi < 4; ++mi) {
    long gm = m0 + wm * 64 + mi * 16 + quad * 4;
#pragma unroll
    for (int ni = 0; ni < 4; ++ni) {
      int gn = n0 + wn * 64 + ni * 16 + nl;
      float bv = bias[gn];
#pragma unroll
      for (int r = 0; r < 4; ++r)
        XT[(gm + r) * 1024 + gn] = (_Float16)(acc[mi][ni][r] + bv);
    }
  }
}

__global__ __launch_bounds__(256) void scores_f_k(const _Float16* __restrict__ XT,
                                                  const _Float16* __restrict__ Xh,
                                                  const float* __restrict__ opin,
                                                  _Float16* __restrict__ P,
                                                  float* __restrict__ denom) {
  __shared__ _Float16 As[128 * 32];
  __shared__ _Float16 Bs[128 * 32];
  const int tid = threadIdx.x;
  const int wave = tid >> 6, lane = tid & 63;
  const int wm = wave >> 1, wn = wave & 1;
  const int quad = lane >> 4, nl = lane & 15;
  const int b = blockIdx.z;
  const int s0 = blockIdx.y * 128;
  const int t0 = blockIdx.x * 128;
  const long base = (long)b * 1024;

  f32x4 acc[4][4];
  f32x4 zero = {0.f, 0.f, 0.f, 0.f};
#pragma unroll
  for (int i = 0; i < 4; ++i)
#pragma unroll
    for (int j = 0; j < 4; ++j) acc[i][j] = zero;

  for (int k0 = 0; k0 < 1024; k0 += 32) {
#pragma unroll
    for (int it = 0; it < 2; ++it) {
      int c = it * 256 + tid;
      gload_lds16(XT + (base + s0 + (c >> 2)) * 1024 + k0 + (c & 3) * 8,
                  &As[(it * 256 + wave * 64) * 8]);
      gload_lds16(Xh + (base + t0 + (c >> 2)) * 1024 + k0 + (c & 3) * 8,
                  &Bs[(it * 256 + wave * 64) * 8]);
    }
    __syncthreads();
    f16x8 af[4], bf[4];
#pragma unroll
    for (int mi = 0; mi < 4; ++mi)
      af[mi] = *(const f16x8*)&As[(wm * 64 + mi * 16 + nl) * 32 + quad * 8];
#pragma unroll
    for (int ni = 0; ni < 4; ++ni)
      bf[ni] = *(const f16x8*)&Bs[(wn * 64 + ni * 16 + nl) * 32 + quad * 8];
#pragma unroll
    for (int mi = 0; mi < 4; ++mi)
#pragma unroll
      for (int ni = 0; ni < 4; ++ni)
        acc[mi][ni] = __builtin_amdgcn_mfma_f32_16x16x32_f16(af[mi], bf[ni], acc[mi][ni], 0, 0, 0);
    __syncthreads();
  }

#pragma unroll
  for (int mi = 0; mi < 4; ++mi) {
#pragma unroll
    for (int r = 0; r < 4; ++r) {
      int s = s0 + wm * 64 + mi * 16 + quad * 4 + r;
      float opv = opin[b * 1024 + s];
      float rs = 0.f;
#pragma unroll
      for (int ni = 0; ni < 4; ++ni) {
        int t = t0 + wn * 64 + ni * 16 + nl;
        float loc = fabsf((float)(s - t));
        float arg = acc[mi][ni][r] * (1.0f / (loc + EPSF)) * opv;
        float th = 1.f - 2.f / (__expf(2.f * arg) + 1.f);
        float p = __expf(th);
        if (s == t) p = 0.f;
        P[(base + s) * 1024 + t] = (_Float16)p;
        rs += p;
      }
      rs += __shfl_xor(rs, 1);
      rs += __shfl_xor(rs, 2);
      rs += __shfl_xor(rs, 4);
      rs += __shfl_xor(rs, 8);
      if (nl == 0) atomicAdd(&denom[b * 1024 + s], rs);
    }
  }
}

__global__ __launch_bounds__(256) void pv_k(const _Float16* __restrict__ P,
                                            const float* __restrict__ X,
                                            const float* __restrict__ denom,
                                            float* __restrict__ out) {
  __shared__ _Float16 As[128 * 32];
  __shared__ _Float16 BsT[128 * 40];
  const int tid = threadIdx.x;
  const int wave = tid >> 6, lane = tid & 63;
  const int wm = wave >> 1, wn = wave & 1;
  const int quad = lane >> 4, nl = lane & 15;
  const int b = blockIdx.z;
  const int s0 = blockIdx.y * 128;
  const int d0 = blockIdx.x * 128;
  const long base = (long)b * 1024;

  const int dcol = tid & 127;
  const int tg = tid >> 7;

  f32x4 acc[4][4];
  f32x4 zero = {0.f, 0.f, 0.f, 0.f};
#pragma unroll
  for (int i = 0; i < 4; ++i)
#pragma unroll
    for (int j = 0; j < 4; ++j) acc[i][j] = zero;

  for (int k0 = 0; k0 < 1024; k0 += 32) {
#pragma unroll
    for (int it = 0; it < 2; ++it) {
      int c = it * 256 + tid;
      gload_lds16(P + (base + s0 + (c >> 2)) * 1024 + k0 + (c & 3) * 8,
                  &As[(it * 256 + wave * 64) * 8]);
    }
    {
      const float* xb = X + (base + k0 + tg * 16) * 1024 + d0 + dcol;
      float v[16];
#pragma unroll
      for (int j = 0; j < 16; ++j) v[j] = xb[j * 1024];
      f16x8 h0, h1;
#pragma unroll
      for (int j = 0; j < 8; ++j) { h0[j] = (_Float16)v[j]; h1[j] = (_Float16)v[8 + j]; }
      *(f16x8*)&BsT[dcol * 40 + tg * 16] = h0;
      *(f16x8*)&BsT[dcol * 40 + tg * 16 + 8] = h1;
    }
    __syncthreads();
    f16x8 af[4], bf[4];
#pragma unroll
    for (int mi = 0; mi < 4; ++mi)
      af[mi] = *(const f16x8*)&As[(wm * 64 + mi * 16 + nl) * 32 + quad * 8];
#pragma unroll
    for (int ni = 0; ni < 4; ++ni)
      bf[ni] = *(const f16x8*)&BsT[(wn * 64 + ni * 16 + nl) * 40 + quad * 8];
#pragma unroll
    for (int mi = 0; mi < 4; ++mi)
#pragma unroll
      for (int ni = 0; ni < 4; ++ni)
        acc[mi][ni] = __builtin_amdgcn_mfma_f32_16x16x32_f16(af[mi], bf[ni], acc[mi][ni], 0, 0, 0);
    __syncthreads();
  }

#pragma unroll
  for (int mi = 0; mi < 4; ++mi) {
#pragma unroll
    for (int r = 0; r < 4; ++r) {
      int s = s0 + wm * 64 + mi * 16 + quad * 4 + r;
      float inv = 1.0f / (denom[b * 1024 + s] + EPSF);
#pragma unroll
      for (int ni = 0; ni < 4; ++ni) {
        int d = d0 + wn * 64 + ni * 16 + nl;
        out[(base + s) * 1024 + d] = acc[mi][ni][r] * inv;
      }
    }
  }
}

extern "C" void kernel_launch(void* const* d_in, const int* in_sizes, int n_in,
                              void* d_out, int out_size, void* d_ws, size_t ws_size,
                              hipStream_t stream) {
  (void)in_sizes; (void)n_in; (void)out_size;
  const int B = 32, S = 1024;
  const int BS = B * S;

  const float* x     = (const float*)d_in[0];
  const float* W     = (const float*)d_in[1];
  const float* bias  = (const float*)d_in[2];
  const float* gold  = (const float*)d_in[3];
  const float* pred  = (const float*)d_in[4];
  const float* gprob = (const float*)d_in[5];

  const size_t P_BYTES  = (size_t)BS * 1024 * sizeof(_Float16);   // 64 MB
  const size_t XT_BYTES = P_BYTES;                                // 64 MB
  const size_t DP_B     = (size_t)16 * BS * sizeof(float);        // 2 MB
  const size_t WH_B     = (size_t)1024 * 1024 * sizeof(_Float16); // 2 MB
  const size_t OPIN_B   = (size_t)BS * sizeof(float);             // 128 KB
  const size_t NEED_BIG = P_BYTES + XT_BYTES + DP_B + WH_B;

  char* ws = (char*)d_ws;
  _Float16* P = (_Float16*)ws;
  const bool big = ws_size >= NEED_BIG;

  // d_out double-duty: front 64MB = XT (fp16), back 64MB = Xh (fp16);
  // both dead before the PV kernel overwrites d_out with fp32 output.
  _Float16* XT = (_Float16*)d_out;
  _Float16* Xh = XT + (size_t)BS * 1024;
  float* out   = (float*)d_out;

  if (big) {
    _Float16* XhT = (_Float16*)(ws + P_BYTES);
    float* dpart  = (float*)(ws + P_BYTES + XT_BYTES);
    _Float16* Wh  = (_Float16*)(ws + P_BYTES + XT_BYTES + DP_B);

    prep_x_k<<<dim3(16, 16, 32), 256, 0, stream>>>(x, Xh, XhT);
    prep_h_k<<<(1024 * 1024 / 8) / 256, 256, 0, stream>>>(W, Wh);
    gemm12_k<<<512, 512, 0, stream>>>(Xh, Wh, bias, XT);
    scores2_k<<<512, 512, 0, stream>>>(XT, Xh, gold, pred, gprob, P, dpart);
    pv2_k<<<512, 512, 0, stream>>>(P, XhT, dpart, out);
  } else {
    float* opin  = (float*)(ws + P_BYTES);
    float* denom = opin + BS;

    hipMemsetAsync(denom, 0, OPIN_B, stream);
    prep_opin_k<<<BS / 256, 256, 0, stream>>>(gold, pred, gprob, opin, BS);
    prep_h_k<<<(BS * 1024 / 8) / 256, 256, 0, stream>>>(x, Xh);
    gemm1_k<<<dim3(8, 256), 256, 0, stream>>>(Xh, W, bias, XT);
    scores_f_k<<<dim3(8, 8, 32), 256, 0, stream>>>(XT, Xh, opin, P, denom);
    pv_k<<<dim3(8, 8, 32), 256, 0, stream>>>(P, x, denom, out);
  }
}

// Round 5
// 478.157 us; speedup vs baseline: 1.2446x; 1.0058x over previous
//
#include <hip/hip_runtime.h>

#define EPSF 1e-5f

typedef _Float16 f16x8 __attribute__((ext_vector_type(8)));
typedef float f32x4 __attribute__((ext_vector_type(4)));

__device__ __forceinline__ void gload_lds16(const _Float16* g, _Float16* l) {
  __builtin_amdgcn_global_load_lds(
      (const __attribute__((address_space(1))) unsigned int*)g,
      (__attribute__((address_space(3))) unsigned int*)l, 16, 0, 0);
}

__device__ __forceinline__ f16x8 cvt8(float4 a, float4 b) {
  f16x8 h;
  h[0] = (_Float16)a.x; h[1] = (_Float16)a.y; h[2] = (_Float16)a.z; h[3] = (_Float16)a.w;
  h[4] = (_Float16)b.x; h[5] = (_Float16)b.y; h[6] = (_Float16)b.z; h[7] = (_Float16)b.w;
  return h;
}

// fast reciprocal: v_rcp_f32 (~1 ulp; inf->0). absmax budget 9.8e-4 >> 1e-7.
__device__ __forceinline__ float frcp(float x) {
  float r;
  asm("v_rcp_f32 %0, %1" : "=v"(r) : "v"(x));
  return r;
}

// ==========================================================================
// 256x256 tile, K=1024 as 32 tiles of BK=32, 8 waves (2M x 4N), ring-4 LDS.
// R5: MINIMAL-BARRIER schedule — ONE s_barrier per tile (was 4). Analysis:
// ring-4 depth means STG at tile T writes buf (T+3)&3 == (T-1)&3, whose
// readers (tile T-1) completed their ds_reads (per-wave lgkm before MFMA)
// BEFORE passing barrier T -> the intra-tile barriers were pure lockstep
// overhead serializing {all-waves ds_read} then {all-waves MFMA} on a SIMD.
// Per tile now: all 12 ds_reads issued up front; lgkmcnt(4) releases
// MFMA16(0) while MFMA16(1)'s 4 reads drain under it (in-order LDS return);
// counted VMW before the single barrier guarantees next buf landed
// collectively. Waves on a SIMD drift within a tile -> wave B's reads
// overlap wave A's MFMA (producer/consumer without role split).
// LDS swizzle unchanged (64B rows, pos p holds chunk p^((row>>1)&3),
// pre-swizzled global src, linear gload_lds dest, same XOR on ds_read).
// ==========================================================================
__device__ __forceinline__ void gemm256_run(const _Float16* __restrict__ Ag,
                                            const _Float16* __restrict__ Bg,
                                            _Float16* lds, f32x4 (&acc)[8][4]) {
  const int tid = threadIdx.x;
  const int wave = tid >> 6, lane = tid & 63;
  const int wm = wave >> 2, wn = wave & 3;
  const int quad = lane >> 4, nl = lane & 15;
  const int swz = (nl >> 1) & 3;  // = (row>>1)&3 for all fragment rows of this lane
  const long stg_off = (long)(tid >> 2) * 1024 + (((tid & 3) ^ ((tid >> 3) & 3)) * 8);

#pragma unroll
  for (int i = 0; i < 8; ++i)
#pragma unroll
    for (int j = 0; j < 4; ++j) acc[i][j] = (f32x4){0.f, 0.f, 0.f, 0.f};

  f16x8 af[4], af2[4], bf[4];

#define STG(G, Tidx, h, isB, SBUF)                                           \
  gload_lds16((G) + (long)(h) * 131072 + stg_off + (Tidx) * 32,              \
              lds + (SBUF) * 16384 + (isB) * 8192 + (h) * 4096 + wave * 512)
#define LDB4(BUF)                                                            \
  {                                                                          \
    const _Float16* pB_ = lds + (BUF) * 16384 + 8192 +                       \
                          (wn * 64 + nl) * 32 + ((quad ^ swz) * 8);          \
    _Pragma("unroll") for (int j_ = 0; j_ < 4; ++j_)                         \
        bf[j_] = *(const f16x8*)(pB_ + j_ * 512);                            \
  }
#define LDA4(BUF, mq, DST)                                                   \
  {                                                                          \
    const _Float16* pA_ = lds + (BUF) * 16384 +                              \
                          (wm * 128 + (mq) * 64 + nl) * 32 + ((quad ^ swz) * 8); \
    _Pragma("unroll") for (int i_ = 0; i_ < 4; ++i_)                         \
        DST[i_] = *(const f16x8*)(pA_ + i_ * 512);                           \
  }
#define MFMA16(mq, SRC)                                                      \
  {                                                                          \
    __builtin_amdgcn_s_setprio(1);                                           \
    _Pragma("unroll") for (int i_ = 0; i_ < 4; ++i_)                         \
        _Pragma("unroll") for (int j_ = 0; j_ < 4; ++j_)                     \
            acc[(mq) * 4 + i_][j_] = __builtin_amdgcn_mfma_f32_16x16x32_f16( \
                SRC[i_], bf[j_], acc[(mq) * 4 + i_][j_], 0, 0, 0);           \
    __builtin_amdgcn_s_setprio(0);                                           \
  }
#define BAR __builtin_amdgcn_s_barrier()
#define SCHED0 __builtin_amdgcn_sched_barrier(0)
#define LGKM4 asm volatile("s_waitcnt lgkmcnt(4)" ::: "memory")
#define LGKM0 asm volatile("s_waitcnt lgkmcnt(0)" ::: "memory")
#define VMW8 asm volatile("s_waitcnt vmcnt(8)" ::: "memory")
#define VMW4 asm volatile("s_waitcnt vmcnt(4)" ::: "memory")
#define VMW0 asm volatile("s_waitcnt vmcnt(0)" ::: "memory")
#define VMNONE
// one tile: 12 ds_reads up front, 4 STG of tile T+3, lgkm(4)-gated MFMA0,
// lgkm(0)-gated MFMA1, counted VMW + ONE barrier at tile end.
#define TILE(T, BUF, SBUF, DOSTG, VW)                                        \
  {                                                                          \
    LDB4(BUF); LDA4(BUF, 0, af);                                             \
    SCHED0;                                                                  \
    LDA4(BUF, 1, af2);                                                       \
    if (DOSTG) { STG(Bg, (T) + 3, 0, 1, SBUF); STG(Bg, (T) + 3, 1, 1, SBUF); \
                 STG(Ag, (T) + 3, 0, 0, SBUF); STG(Ag, (T) + 3, 1, 0, SBUF); } \
    LGKM4; SCHED0; MFMA16(0, af);                                            \
    LGKM0; SCHED0; MFMA16(1, af2);                                           \
    VW; SCHED0; BAR;                                                         \
  }

  // prologue: stage tiles 0,1,2 (12 loads); vmcnt(8) -> tile0's 4 landed
  STG(Bg, 0, 0, 1, 0); STG(Bg, 0, 1, 1, 0); STG(Ag, 0, 0, 0, 0); STG(Ag, 0, 1, 0, 0);
  STG(Bg, 1, 0, 1, 1); STG(Bg, 1, 1, 1, 1); STG(Ag, 1, 0, 0, 1); STG(Ag, 1, 1, 0, 1);
  STG(Bg, 2, 0, 1, 2); STG(Bg, 2, 1, 1, 2); STG(Ag, 2, 0, 0, 2); STG(Ag, 2, 1, 0, 2);
  VMW8;
  BAR;

  for (int TT = 0; TT < 28; TT += 4) {
    TILE(TT + 0, 0, 3, true, VMW8);
    TILE(TT + 1, 1, 0, true, VMW8);
    TILE(TT + 2, 2, 1, true, VMW8);
    TILE(TT + 3, 3, 2, true, VMW8);
  }
  TILE(28, 0, 3, true, VMW8);   // stages tile 31 into buf 3
  TILE(29, 1, 0, false, VMW4);  // drain: tile 30's loads land
  TILE(30, 2, 0, false, VMW0);  // drain: tile 31's loads land
  TILE(31, 3, 0, false, VMNONE);

#undef TILE
#undef VMNONE
#undef VMW0
#undef VMW4
#undef VMW8
#undef LGKM0
#undef LGKM4
#undef SCHED0
#undef BAR
#undef MFMA16
#undef LDA4
#undef LDB4
#undef STG
}

// ================= kernel 0a: opinion weights (fallback path only) ============
__global__ void prep_opin_k(const float* __restrict__ gold, const float* __restrict__ pred,
                            const float* __restrict__ gprob, float* __restrict__ opin, int n) {
  int i = blockIdx.x * 256 + threadIdx.x;
  if (i >= n) return;
  float gp = gprob[0];
  float go = gold[i * 5 + 1] + gold[i * 5 + 2];
  float po = pred[i * 5 + 3] + pred[i * 5 + 4];
  opin[i] = gp * go + (1.0f - gp) * po;
}

// ================= kernel 0b: fp32 -> fp16 copy (W->Wh; fallback x->Xh) =======
__global__ __launch_bounds__(256) void prep_h_k(const float* __restrict__ src,
                                                _Float16* __restrict__ dst) {
  long i = ((long)blockIdx.x * 256 + threadIdx.x) * 8;
  float4 a = *(const float4*)(src + i);
  float4 b = *(const float4*)(src + i + 4);
  *(f16x8*)(dst + i) = cvt8(a, b);
}

// ===== kernel 0c (fused): Xh = fp16(x), XhT[b][d][t] = fp16(x[b][t][d]) =======
__global__ __launch_bounds__(256) void prep_x_k(const float* __restrict__ x,
                                                _Float16* __restrict__ Xh,
                                                _Float16* __restrict__ XhT) {
  __shared__ _Float16 T[64][66];  // ld=66 -> 2-way max on both sides
  const int d0 = blockIdx.x * 64, t0 = blockIdx.y * 64;
  const long base = (long)blockIdx.z * 1024;
  const int c = threadIdx.x & 63, tr = threadIdx.x >> 6;
#pragma unroll
  for (int k = 0; k < 16; ++k) {
    int t = k * 4 + tr;
    float v = x[(base + t0 + t) * 1024 + d0 + c];
    _Float16 h = (_Float16)v;
    Xh[(base + t0 + t) * 1024 + d0 + c] = h;
    T[t][c] = h;
  }
  __syncthreads();
#pragma unroll
  for (int k = 0; k < 16; ++k) {
    int d = k * 4 + tr;
    XhT[(base + d0 + d) * 1024 + t0 + c] = T[c][d];
  }
}

// ================= kernel 1 (big): XT = fp16(Xh @ Wh^T + b) ====================
__global__ __launch_bounds__(512, 2) void gemm12_k(const _Float16* __restrict__ Xh,
                                                   const _Float16* __restrict__ Wh,
                                                   const float* __restrict__ bias,
                                                   _Float16* __restrict__ XT) {
  __shared__ _Float16 lds[4 * 16384];
  const int lin = blockIdx.x;
  const int ii = lin >> 3;
  const int mt = (lin & 7) * 16 + (ii >> 2);
  const int nt = ii & 3;
  const long m0 = (long)mt * 256;
  const int n0 = nt * 256;

  f32x4 acc[8][4];
  gemm256_run(Xh + m0 * 1024, Wh + (long)n0 * 1024, lds, acc);

  const int tid = threadIdx.x;
  const int wave = tid >> 6, lane = tid & 63;
  const int wm = wave >> 2, wn = wave & 3;
  const int quad = lane >> 4, nl = lane & 15;
#pragma unroll
  for (int mi = 0; mi < 8; ++mi) {
    long gm = m0 + wm * 128 + mi * 16 + quad * 4;
#pragma unroll
    for (int ni = 0; ni < 4; ++ni) {
      int gn = n0 + wn * 64 + ni * 16 + nl;
      float bv = bias[gn];
#pragma unroll
      for (int r = 0; r < 4; ++r)
        XT[(gm + r) * 1024 + gn] = (_Float16)(acc[mi][ni][r] + bv);
    }
  }
}

// ======= kernel 2 (big): P = fp16(exp(tanh(XT@Xh^T * decay * opin))) ==========
__global__ __launch_bounds__(512, 2) void scores2_k(const _Float16* __restrict__ XT,
                                                    const _Float16* __restrict__ Xh,
                                                    const float* __restrict__ gold,
                                                    const float* __restrict__ pred,
                                                    const float* __restrict__ gprob,
                                                    _Float16* __restrict__ P,
                                                    float* __restrict__ dpart) {
  __shared__ _Float16 lds[4 * 16384];
  const int lin = blockIdx.x;
  const int ii = lin >> 3;
  const int b = (lin & 7) + 8 * (ii >> 4);
  const int tile = ii & 15;
  const int s0 = (tile >> 2) * 256;
  const int t0 = (tile & 3) * 256;
  const long base = (long)b * 1024;

  f32x4 acc[8][4];
  gemm256_run(XT + (base + s0) * 1024, Xh + (base + t0) * 1024, lds, acc);
  // sop targets buf0 (lds[0..1023]); tiles 29-31 only read bufs 1-3 and
  // barrier drift is <1 tile, so no overlap with any in-flight reader.

  const int tid = threadIdx.x;
  float* sop = (float*)lds;
  if (tid < 256) {
    int s = s0 + tid;
    float gp = gprob[0];
    long o = (base + s) * 5;
    float go = gold[o + 1] + gold[o + 2];
    float po = pred[o + 3] + pred[o + 4];
    sop[tid] = gp * go + (1.0f - gp) * po;
  }
  __syncthreads();

  const int wave = tid >> 6, lane = tid & 63;
  const int wm = wave >> 2, wn = wave & 3;
  const int quad = lane >> 4, nl = lane & 15;
  const int slice = (tile & 3) * 4 + wn;
#pragma unroll
  for (int mi = 0; mi < 8; ++mi) {
#pragma unroll
    for (int r = 0; r < 4; ++r) {
      int sl = wm * 128 + mi * 16 + quad * 4 + r;  // s - s0
      int s = s0 + sl;
      float opv = sop[sl];
      float rs = 0.f;
#pragma unroll
      for (int ni = 0; ni < 4; ++ni) {
        int tc = t0 + wn * 64 + ni * 16 + nl;
        float loc = fabsf((float)(s - tc));
        float arg = acc[mi][ni][r] * frcp(loc + EPSF) * opv;
        float th = 1.f - 2.f * frcp(__expf(2.f * arg) + 1.f);  // tanh(arg)
        float p = __expf(th);
        if (s == tc) p = 0.f;
        P[(base + s) * 1024 + tc] = (_Float16)p;
        rs += p;
      }
      rs += __shfl_xor(rs, 1);
      rs += __shfl_xor(rs, 2);
      rs += __shfl_xor(rs, 4);
      rs += __shfl_xor(rs, 8);
      if (nl == 0) dpart[(((long)slice * 32 + b) << 10) + s] = rs;
    }
  }
}

// ================= kernel 3 (big): out = (P @ XhT^T) / (denom + eps) ==========
__global__ __launch_bounds__(512, 2) void pv2_k(const _Float16* __restrict__ P,
                                                const _Float16* __restrict__ XhT,
                                                const float* __restrict__ dpart,
                                                float* __restrict__ out) {
  __shared__ _Float16 lds[4 * 16384];
  const int lin = blockIdx.x;
  const int ii = lin >> 3;
  const int b = (lin & 7) + 8 * (ii >> 4);
  const int tile = ii & 15;
  const int s0 = (tile >> 2) * 256;
  const int d0 = (tile & 3) * 256;
  const long base = (long)b * 1024;

  f32x4 acc[8][4];
  gemm256_run(P + (base + s0) * 1024, XhT + (base + d0) * 1024, lds, acc);

  const int tid = threadIdx.x;
  float* sden = (float*)lds;
  if (tid < 256) {
    float sum = 0.f;
#pragma unroll
    for (int k = 0; k < 16; ++k)
      sum += dpart[(((long)k * 32 + b) << 10) + s0 + tid];
    sden[tid] = frcp(sum + EPSF);
  }
  __syncthreads();

  const int wave = tid >> 6, lane = tid & 63;
  const int wm = wave >> 2, wn = wave & 3;
  const int quad = lane >> 4, nl = lane & 15;
#pragma unroll
  for (int mi = 0; mi < 8; ++mi) {
#pragma unroll
    for (int r = 0; r < 4; ++r) {
      int sl = wm * 128 + mi * 16 + quad * 4 + r;
      int s = s0 + sl;
      float inv = sden[sl];
#pragma unroll
      for (int ni = 0; ni < 4; ++ni) {
        int d = d0 + wn * 64 + ni * 16 + nl;
        out[(base + s) * 1024 + d] = acc[mi][ni][r] * inv;
      }
    }
  }
}

// =================== fallback path (small ws) — unchanged 128^2 kernels =========
__global__ __launch_bounds__(256) void gemm1_k(const _Float16* __restrict__ Xh,
                                               const float* __restrict__ Wt,
                                               const float* __restrict__ bias,
                                               _Float16* __restrict__ XT) {
  __shared__ _Float16 As[128 * 32];
  __shared__ _Float16 Bs[128 * 32];
  const int tid = threadIdx.x;
  const int wave = tid >> 6, lane = tid & 63;
  const int wm = wave >> 1, wn = wave & 1;
  const int quad = lane >> 4, nl = lane & 15;
  const long m0 = (long)blockIdx.y * 128;
  const int n0 = blockIdx.x * 128;

  f32x4 acc[4][4];
  f32x4 zero = {0.f, 0.f, 0.f, 0.f};
#pragma unroll
  for (int i = 0; i < 4; ++i)
#pragma unroll
    for (int j = 0; j < 4; ++j) acc[i][j] = zero;

  const int crow = tid >> 2;
  const int ckc = (tid & 3) * 8;

  for (int k0 = 0; k0 < 1024; k0 += 32) {
#pragma unroll
    for (int it = 0; it < 2; ++it) {
      int c = it * 256 + tid;
      gload_lds16(Xh + (m0 + (c >> 2)) * 1024 + k0 + (c & 3) * 8,
                  &As[(it * 256 + wave * 64) * 8]);
      int row = it * 64 + crow;
      const float* sb = Wt + (long)(n0 + row) * 1024 + k0 + ckc;
      float4 b0 = *(const float4*)sb;
      float4 b1 = *(const float4*)(sb + 4);
      *(f16x8*)&Bs[row * 32 + ckc] = cvt8(b0, b1);
    }
    __syncthreads();
    f16x8 af[4], bf[4];
#pragma unroll
    for (int mi = 0; mi < 4; ++mi)
      af[mi] = *(const f16x8*)&As[(wm * 64 + mi * 16 + nl) * 32 + quad * 8];
#pragma unroll
    for (int ni = 0; ni < 4; ++ni)
      bf[ni] = *(const f16x8*)&Bs[(wn * 64 + ni * 16 + nl) * 32 + quad * 8];
#pragma unroll
    for (int mi = 0; mi < 4; ++mi)
#pragma unroll
      for (int ni = 0; ni < 4; ++ni)
        acc[mi][ni] = __builtin_amdgcn_mfma_f32_16x16x32_f16(af[mi], bf[ni], acc[mi][ni], 0, 0, 0);
    __syncthreads();
  }

#pragma unroll
  for (int mi = 0; mi < 4; ++mi) {
    long gm = m0 + wm * 64 + mi * 16 + quad * 4;
#pragma unroll
    for (int ni = 0; ni < 4; ++ni) {
      int gn = n0 + wn * 64 + ni * 16 + nl;
      float bv = bias[gn];
#pragma unroll
      for (int r = 0; r < 4; ++r)
        XT[(gm + r) * 1024 + gn] = (_Float16)(acc[mi][ni][r] + bv);
    }
  }
}

__global__ __launch_bounds__(256) void scores_f_k(const _Float16* __restrict__ XT,
                                                  const _Float16* __restrict__ Xh,
                                                  const float* __restrict__ opin,
                                                  _Float16* __restrict__ P,
                                                  float* __restrict__ denom) {
  __shared__ _Float16 As[128 * 32];
  __shared__ _Float16 Bs[128 * 32];
  const int tid = threadIdx.x;
  const int wave = tid >> 6, lane = tid & 63;
  const int wm = wave >> 1, wn = wave & 1;
  const int quad = lane >> 4, nl = lane & 15;
  const int b = blockIdx.z;
  const int s0 = blockIdx.y * 128;
  const int t0 = blockIdx.x * 128;
  const long base = (long)b * 1024;

  f32x4 acc[4][4];
  f32x4 zero = {0.f, 0.f, 0.f, 0.f};
#pragma unroll
  for (int i = 0; i < 4; ++i)
#pragma unroll
    for (int j = 0; j < 4; ++j) acc[i][j] = zero;

  for (int k0 = 0; k0 < 1024; k0 += 32) {
#pragma unroll
    for (int it = 0; it < 2; ++it) {
      int c = it * 256 + tid;
      gload_lds16(XT + (base + s0 + (c >> 2)) * 1024 + k0 + (c & 3) * 8,
                  &As[(it * 256 + wave * 64) * 8]);
      gload_lds16(Xh + (base + t0 + (c >> 2)) * 1024 + k0 + (c & 3) * 8,
                  &Bs[(it * 256 + wave * 64) * 8]);
    }
    __syncthreads();
    f16x8 af[4], bf[4];
#pragma unroll
    for (int mi = 0; mi < 4; ++mi)
      af[mi] = *(const f16x8*)&As[(wm * 64 + mi * 16 + nl) * 32 + quad * 8];
#pragma unroll
    for (int ni = 0; ni < 4; ++ni)
      bf[ni] = *(const f16x8*)&Bs[(wn * 64 + ni * 16 + nl) * 32 + quad * 8];
#pragma unroll
    for (int mi = 0; mi < 4; ++mi)
#pragma unroll
      for (int ni = 0; ni < 4; ++ni)
        acc[mi][ni] = __builtin_amdgcn_mfma_f32_16x16x32_f16(af[mi], bf[ni], acc[mi][ni], 0, 0, 0);
    __syncthreads();
  }

#pragma unroll
  for (int mi = 0; mi < 4; ++mi) {
#pragma unroll
    for (int r = 0; r < 4; ++r) {
      int s = s0 + wm * 64 + mi * 16 + quad * 4 + r;
      float opv = opin[b * 1024 + s];
      float rs = 0.f;
#pragma unroll
      for (int ni = 0; ni < 4; ++ni) {
        int t = t0 + wn * 64 + ni * 16 + nl;
        float loc = fabsf((float)(s - t));
        float arg = acc[mi][ni][r] * (1.0f / (loc + EPSF)) * opv;
        float th = 1.f - 2.f / (__expf(2.f * arg) + 1.f);
        float p = __expf(th);
        if (s == t) p = 0.f;
        P[(base + s) * 1024 + t] = (_Float16)p;
        rs += p;
      }
      rs += __shfl_xor(rs, 1);
      rs += __shfl_xor(rs, 2);
      rs += __shfl_xor(rs, 4);
      rs += __shfl_xor(rs, 8);
      if (nl == 0) atomicAdd(&denom[b * 1024 + s], rs);
    }
  }
}

__global__ __launch_bounds__(256) void pv_k(const _Float16* __restrict__ P,
                                            const float* __restrict__ X,
                                            const float* __restrict__ denom,
                                            float* __restrict__ out) {
  __shared__ _Float16 As[128 * 32];
  __shared__ _Float16 BsT[128 * 40];
  const int tid = threadIdx.x;
  const int wave = tid >> 6, lane = tid & 63;
  const int wm = wave >> 1, wn = wave & 1;
  const int quad = lane >> 4, nl = lane & 15;
  const int b = blockIdx.z;
  const int s0 = blockIdx.y * 128;
  const int d0 = blockIdx.x * 128;
  const long base = (long)b * 1024;

  const int dcol = tid & 127;
  const int tg = tid >> 7;

  f32x4 acc[4][4];
  f32x4 zero = {0.f, 0.f, 0.f, 0.f};
#pragma unroll
  for (int i = 0; i < 4; ++i)
#pragma unroll
    for (int j = 0; j < 4; ++j) acc[i][j] = zero;

  for (int k0 = 0; k0 < 1024; k0 += 32) {
#pragma unroll
    for (int it = 0; it < 2; ++it) {
      int c = it * 256 + tid;
      gload_lds16(P + (base + s0 + (c >> 2)) * 1024 + k0 + (c & 3) * 8,
                  &As[(it * 256 + wave * 64) * 8]);
    }
    {
      const float* xb = X + (base + k0 + tg * 16) * 1024 + d0 + dcol;
      float v[16];
#pragma unroll
      for (int j = 0; j < 16; ++j) v[j] = xb[j * 1024];
      f16x8 h0, h1;
#pragma unroll
      for (int j = 0; j < 8; ++j) { h0[j] = (_Float16)v[j]; h1[j] = (_Float16)v[8 + j]; }
      *(f16x8*)&BsT[dcol * 40 + tg * 16] = h0;
      *(f16x8*)&BsT[dcol * 40 + tg * 16 + 8] = h1;
    }
    __syncthreads();
    f16x8 af[4], bf[4];
#pragma unroll
    for (int mi = 0; mi < 4; ++mi)
      af[mi] = *(const f16x8*)&As[(wm * 64 + mi * 16 + nl) * 32 + quad * 8];
#pragma unroll
    for (int ni = 0; ni < 4; ++ni)
      bf[ni] = *(const f16x8*)&BsT[(wn * 64 + ni * 16 + nl) * 40 + quad * 8];
#pragma unroll
    for (int mi = 0; mi < 4; ++mi)
#pragma unroll
      for (int ni = 0; ni < 4; ++ni)
        acc[mi][ni] = __builtin_amdgcn_mfma_f32_16x16x32_f16(af[mi], bf[ni], acc[mi][ni], 0, 0, 0);
    __syncthreads();
  }

#pragma unroll
  for (int mi = 0; mi < 4; ++mi) {
#pragma unroll
    for (int r = 0; r < 4; ++r) {
      int s = s0 + wm * 64 + mi * 16 + quad * 4 + r;
      float inv = 1.0f / (denom[b * 1024 + s] + EPSF);
#pragma unroll
      for (int ni = 0; ni < 4; ++ni) {
        int d = d0 + wn * 64 + ni * 16 + nl;
        out[(base + s) * 1024 + d] = acc[mi][ni][r] * inv;
      }
    }
  }
}

extern "C" void kernel_launch(void* const* d_in, const int* in_sizes, int n_in,
                              void* d_out, int out_size, void* d_ws, size_t ws_size,
                              hipStream_t stream) {
  (void)in_sizes; (void)n_in; (void)out_size;
  const int B = 32, S = 1024;
  const int BS = B * S;

  const float* x     = (const float*)d_in[0];
  const float* W     = (const float*)d_in[1];
  const float* bias  = (const float*)d_in[2];
  const float* gold  = (const float*)d_in[3];
  const float* pred  = (const float*)d_in[4];
  const float* gprob = (const float*)d_in[5];

  const size_t P_BYTES  = (size_t)BS * 1024 * sizeof(_Float16);   // 64 MB
  const size_t XT_BYTES = P_BYTES;                                // 64 MB
  const size_t DP_B     = (size_t)16 * BS * sizeof(float);        // 2 MB
  const size_t WH_B     = (size_t)1024 * 1024 * sizeof(_Float16); // 2 MB
  const size_t OPIN_B   = (size_t)BS * sizeof(float);             // 128 KB
  const size_t NEED_BIG = P_BYTES + XT_BYTES + DP_B + WH_B;

  char* ws = (char*)d_ws;
  _Float16* P = (_Float16*)ws;
  const bool big = ws_size >= NEED_BIG;

  // d_out double-duty: front 64MB = XT (fp16), back 64MB = Xh (fp16);
  // both dead before the PV kernel overwrites d_out with fp32 output.
  _Float16* XT = (_Float16*)d_out;
  _Float16* Xh = XT + (size_t)BS * 1024;
  float* out   = (float*)d_out;

  if (big) {
    _Float16* XhT = (_Float16*)(ws + P_BYTES);
    float* dpart  = (float*)(ws + P_BYTES + XT_BYTES);
    _Float16* Wh  = (_Float16*)(ws + P_BYTES + XT_BYTES + DP_B);

    prep_x_k<<<dim3(16, 16, 32), 256, 0, stream>>>(x, Xh, XhT);
    prep_h_k<<<(1024 * 1024 / 8) / 256, 256, 0, stream>>>(W, Wh);
    gemm12_k<<<512, 512, 0, stream>>>(Xh, Wh, bias, XT);
    scores2_k<<<512, 512, 0, stream>>>(XT, Xh, gold, pred, gprob, P, dpart);
    pv2_k<<<512, 512, 0, stream>>>(P, XhT, dpart, out);
  } else {
    float* opin  = (float*)(ws + P_BYTES);
    float* denom = opin + BS;

    hipMemsetAsync(denom, 0, OPIN_B, stream);
    prep_opin_k<<<BS / 256, 256, 0, stream>>>(gold, pred, gprob, opin, BS);
    prep_h_k<<<(BS * 1024 / 8) / 256, 256, 0, stream>>>(x, Xh);
    gemm1_k<<<dim3(8, 256), 256, 0, stream>>>(Xh, W, bias, XT);
    scores_f_k<<<dim3(8, 8, 32), 256, 0, stream>>>(XT, Xh, opin, P, denom);
    pv_k<<<dim3(8, 8, 32), 256, 0, stream>>>(P, x, denom, out);
  }
}